// Round 1
// baseline (1319.356 us; speedup 1.0000x reference)
//
#include <hip/hip_runtime.h>
#include <hip/hip_bf16.h>

// Problem constants (CompactCrossAttention)
#define Bb   2
#define QL   1024
#define KL   4096
#define Hh   1024
#define NH   16
#define HD   64

// ---------------------------------------------------------------------------
// Generic fp32 GEMM: C[M,N] = A[M,K] @ B[K,N], all row-major.
// 128x128 block tile, BK=16, 256 threads, 8x8 micro-tile per thread
// (split as 4+4 rows/cols with stride 64 to avoid LDS bank conflicts).
// ---------------------------------------------------------------------------
#define BM 128
#define BN 128
#define BK 16

__global__ __launch_bounds__(256) void gemm_f32(const float* __restrict__ A,
                                                const float* __restrict__ B,
                                                float* __restrict__ C,
                                                int M, int N, int K) {
    __shared__ float As[BK][BM + 4];   // [k][m], pad 4 -> stride 132
    __shared__ float Bs[BK][BN + 4];   // [k][n]

    const int tid = threadIdx.x;
    const int tx  = tid & 15;          // 0..15  (cols)
    const int ty  = tid >> 4;          // 0..15  (rows)
    const int row0 = blockIdx.y * BM;
    const int col0 = blockIdx.x * BN;

    // A tile loader: 128 rows x 16 k. thread -> (a_r, a_c), 2 passes of rows.
    const int a_r = tid >> 2;          // 0..63
    const int a_c = (tid & 3) * 4;     // 0,4,8,12
    // B tile loader: 16 k x 128 n. 2 passes of k-rows.
    const int b_r = tid >> 5;          // 0..7
    const int b_c = (tid & 31) * 4;    // 0..124

    float acc[8][8];
#pragma unroll
    for (int i = 0; i < 8; ++i)
#pragma unroll
        for (int j = 0; j < 8; ++j) acc[i][j] = 0.f;

    for (int k0 = 0; k0 < K; k0 += BK) {
        // global -> LDS
#pragma unroll
        for (int it = 0; it < 2; ++it) {
            const int r = a_r + it * 64;
            float4 v = *reinterpret_cast<const float4*>(
                &A[(size_t)(row0 + r) * K + k0 + a_c]);
            As[a_c + 0][r] = v.x;
            As[a_c + 1][r] = v.y;
            As[a_c + 2][r] = v.z;
            As[a_c + 3][r] = v.w;
        }
#pragma unroll
        for (int it = 0; it < 2; ++it) {
            const int r = b_r + it * 8;
            *reinterpret_cast<float4*>(&Bs[r][b_c]) =
                *reinterpret_cast<const float4*>(
                    &B[(size_t)(k0 + r) * N + col0 + b_c]);
        }
        __syncthreads();

#pragma unroll
        for (int k = 0; k < BK; ++k) {
            float a[8], bb[8];
            *reinterpret_cast<float4*>(&a[0]) =
                *reinterpret_cast<const float4*>(&As[k][ty * 4]);
            *reinterpret_cast<float4*>(&a[4]) =
                *reinterpret_cast<const float4*>(&As[k][64 + ty * 4]);
            *reinterpret_cast<float4*>(&bb[0]) =
                *reinterpret_cast<const float4*>(&Bs[k][tx * 4]);
            *reinterpret_cast<float4*>(&bb[4]) =
                *reinterpret_cast<const float4*>(&Bs[k][64 + tx * 4]);
#pragma unroll
            for (int i = 0; i < 8; ++i)
#pragma unroll
                for (int j = 0; j < 8; ++j) acc[i][j] += a[i] * bb[j];
        }
        __syncthreads();
    }

    // store: rows = row0 + {ty*4+i2, 64+ty*4+i2}, cols = col0 + {tx*4+j2, 64+tx*4+j2}
#pragma unroll
    for (int ih = 0; ih < 2; ++ih) {
#pragma unroll
        for (int i2 = 0; i2 < 4; ++i2) {
            const int i = ih * 4 + i2;
            const size_t r = (size_t)(row0 + ih * 64 + ty * 4 + i2);
#pragma unroll
            for (int jh = 0; jh < 2; ++jh) {
                float4 v = make_float4(acc[i][jh * 4 + 0], acc[i][jh * 4 + 1],
                                       acc[i][jh * 4 + 2], acc[i][jh * 4 + 3]);
                *reinterpret_cast<float4*>(
                    &C[r * N + col0 + jh * 64 + tx * 4]) = v;
            }
        }
    }
}

// ---------------------------------------------------------------------------
// fp32 flash attention.
// Grid: B * NH * (QL/64) blocks, 256 threads (4 waves).
// Block handles one (b, h) and 64 q-rows; loops over KL in 64-key tiles.
// Thread (ty,tx) [16x16 grid] owns q-rows ty*4..+3 and (keys | d-cols) tx*4..+3.
// Q/K staged transposed in LDS ([d][row], pad 68) for float4 reads along d.
// Online softmax: row stats reduced across the 16 tx-lanes (same wave,
// width-16 shfl_xor). P broadcast for PV via __shfl (no LDS P tile).
// Output written directly in [B, QL, H] layout (transpose folded in).
// ---------------------------------------------------------------------------
__global__ __launch_bounds__(256) void attn_f32(const float* __restrict__ Q,   // [B,QL,H]
                                                const float* __restrict__ KV,  // [B,KL,2H]
                                                float* __restrict__ O) {       // [B,QL,H]
    __shared__ float QsT[64][68];   // [d][q]
    __shared__ float KsT[64][68];   // [d][k]
    __shared__ float Vs[64][68];    // [k][d]

    const int bid = blockIdx.x;
    const int qb  = bid & 15;          // QL/64 = 16
    const int h   = (bid >> 4) & 15;   // NH = 16
    const int b   = bid >> 8;
    const int tid = threadIdx.x;
    const int tx  = tid & 15;
    const int ty  = tid >> 4;
    const int q0  = qb * 64;

    // Load Q tile transposed: QsT[d][r] = Q[b][q0+r][h*64+d]
    {
        const int r  = tid >> 2;          // 0..63
        const int dq = (tid & 3) * 16;    // 0,16,32,48
        const float* src = Q + ((size_t)(b * QL + q0 + r) * Hh + h * HD);
#pragma unroll
        for (int ii = 0; ii < 4; ++ii) {
            float4 v = *reinterpret_cast<const float4*>(src + dq + ii * 4);
            QsT[dq + ii * 4 + 0][r] = v.x;
            QsT[dq + ii * 4 + 1][r] = v.y;
            QsT[dq + ii * 4 + 2][r] = v.z;
            QsT[dq + ii * 4 + 3][r] = v.w;
        }
    }

    float m_i[4], l_i[4], o[4][4];
#pragma unroll
    for (int i = 0; i < 4; ++i) {
        m_i[i] = -1e30f;
        l_i[i] = 0.f;
#pragma unroll
        for (int j = 0; j < 4; ++j) o[i][j] = 0.f;
    }

    const float scale = 0.125f;   // 1/sqrt(64)

    for (int k0 = 0; k0 < KL; k0 += 64) {
        __syncthreads();   // protect prior-iter LDS reads (also orders Qs writes)
        // Load K tile (transposed) + V tile
        {
            const int r  = tid >> 2;
            const int dq = (tid & 3) * 16;
            const float* kvrow = KV + (size_t)(b * KL + k0 + r) * (2 * Hh);
            const float* ksrc  = kvrow + h * HD;
            const float* vsrc  = kvrow + Hh + h * HD;
#pragma unroll
            for (int ii = 0; ii < 4; ++ii) {
                float4 kk = *reinterpret_cast<const float4*>(ksrc + dq + ii * 4);
                KsT[dq + ii * 4 + 0][r] = kk.x;
                KsT[dq + ii * 4 + 1][r] = kk.y;
                KsT[dq + ii * 4 + 2][r] = kk.z;
                KsT[dq + ii * 4 + 3][r] = kk.w;
                *reinterpret_cast<float4*>(&Vs[r][dq + ii * 4]) =
                    *reinterpret_cast<const float4*>(vsrc + dq + ii * 4);
            }
        }
        __syncthreads();

        // Phase 1: S[4][4] = Q K^T for this thread's (rows, keys)
        float s[4][4];
#pragma unroll
        for (int i = 0; i < 4; ++i)
#pragma unroll
            for (int j = 0; j < 4; ++j) s[i][j] = 0.f;

#pragma unroll 4
        for (int d = 0; d < 64; ++d) {
            float4 a  = *reinterpret_cast<const float4*>(&QsT[d][ty * 4]);
            float4 kk = *reinterpret_cast<const float4*>(&KsT[d][tx * 4]);
            const float av[4] = {a.x, a.y, a.z, a.w};
            const float kv[4] = {kk.x, kk.y, kk.z, kk.w};
#pragma unroll
            for (int i = 0; i < 4; ++i)
#pragma unroll
                for (int j = 0; j < 4; ++j) s[i][j] += av[i] * kv[j];
        }

        // Phase 2: online softmax (row-group = 16 tx lanes of same wave)
        float p[4][4];
#pragma unroll
        for (int i = 0; i < 4; ++i) {
            float mx = fmaxf(fmaxf(s[i][0], s[i][1]), fmaxf(s[i][2], s[i][3])) * scale;
            mx = fmaxf(mx, __shfl_xor(mx, 1, 16));
            mx = fmaxf(mx, __shfl_xor(mx, 2, 16));
            mx = fmaxf(mx, __shfl_xor(mx, 4, 16));
            mx = fmaxf(mx, __shfl_xor(mx, 8, 16));
            const float mnew  = fmaxf(m_i[i], mx);
            const float alpha = __expf(m_i[i] - mnew);
            float sum = 0.f;
#pragma unroll
            for (int j = 0; j < 4; ++j) {
                p[i][j] = __expf(s[i][j] * scale - mnew);
                sum += p[i][j];
            }
            sum += __shfl_xor(sum, 1, 16);
            sum += __shfl_xor(sum, 2, 16);
            sum += __shfl_xor(sum, 4, 16);
            sum += __shfl_xor(sum, 8, 16);
            l_i[i] = alpha * l_i[i] + sum;
            m_i[i] = mnew;
#pragma unroll
            for (int j = 0; j < 4; ++j) o[i][j] *= alpha;
        }

        // Phase 3: O += P @ V.  P[q][kk] broadcast from owner lane via shfl.
        for (int kk4 = 0; kk4 < 16; ++kk4) {
            const int srcLane = ((ty & 3) << 4) + kk4;   // lane within this wave
#pragma unroll
            for (int jj = 0; jj < 4; ++jj) {
                const int kk = kk4 * 4 + jj;
                float4 v = *reinterpret_cast<const float4*>(&Vs[kk][tx * 4]);
                const float pv0 = __shfl(p[0][jj], srcLane, 64);
                const float pv1 = __shfl(p[1][jj], srcLane, 64);
                const float pv2 = __shfl(p[2][jj], srcLane, 64);
                const float pv3 = __shfl(p[3][jj], srcLane, 64);
                o[0][0] += pv0 * v.x; o[0][1] += pv0 * v.y; o[0][2] += pv0 * v.z; o[0][3] += pv0 * v.w;
                o[1][0] += pv1 * v.x; o[1][1] += pv1 * v.y; o[1][2] += pv1 * v.z; o[1][3] += pv1 * v.w;
                o[2][0] += pv2 * v.x; o[2][1] += pv2 * v.y; o[2][2] += pv2 * v.z; o[2][3] += pv2 * v.w;
                o[3][0] += pv3 * v.x; o[3][1] += pv3 * v.y; o[3][2] += pv3 * v.z; o[3][3] += pv3 * v.w;
            }
        }
    }

    // Epilogue: normalize and write [B, QL, H] (attention-out transpose folded)
#pragma unroll
    for (int i = 0; i < 4; ++i) {
        const float inv = 1.f / l_i[i];
        float4 v = make_float4(o[i][0] * inv, o[i][1] * inv,
                               o[i][2] * inv, o[i][3] * inv);
        *reinterpret_cast<float4*>(
            &O[(size_t)(b * QL + q0 + ty * 4 + i) * Hh + h * HD + tx * 4]) = v;
    }
}

// ---------------------------------------------------------------------------
// Launch
// ---------------------------------------------------------------------------
extern "C" void kernel_launch(void* const* d_in, const int* in_sizes, int n_in,
                              void* d_out, int out_size, void* d_ws, size_t ws_size,
                              hipStream_t stream) {
    const float* query     = (const float*)d_in[0];  // [2,1024,1024]
    const float* key_value = (const float*)d_in[1];  // [2,4096,1024]
    const float* w_q       = (const float*)d_in[2];  // [1024,1024]
    const float* w_kv      = (const float*)d_in[3];  // [1024,2048]
    const float* w_out     = (const float*)d_in[4];  // [1024,1024]
    float* out = (float*)d_out;                      // [2,1024,1024]

    char* ws = (char*)d_ws;
    float* Qp  = (float*)(ws);                                  //  8 MB: [2048,1024]
    float* KVp = (float*)(ws + (size_t)8 * 1024 * 1024);        // 64 MB: [8192,2048]
    float* AOp = (float*)(ws + (size_t)72 * 1024 * 1024);       //  8 MB: [2048,1024]

    dim3 blk(256);

    // 1) Q = query @ w_q            [2048,1024]
    gemm_f32<<<dim3(1024 / BN, 2048 / BM), blk, 0, stream>>>(
        query, w_q, Qp, Bb * QL, Hh, Hh);

    // 2) KV = key_value @ w_kv      [8192,2048]  (K = cols 0..1023, V = 1024..2047)
    gemm_f32<<<dim3(2048 / BN, 8192 / BM), blk, 0, stream>>>(
        key_value, w_kv, KVp, Bb * KL, 2 * Hh, Hh);

    // 3) flash attention -> AO [2,1024,1024] (already in [B,QL,H] layout)
    attn_f32<<<dim3(Bb * NH * (QL / 64)), blk, 0, stream>>>(Qp, KVp, AOp);

    // 4) out = AO @ w_out           [2048,1024]
    gemm_f32<<<dim3(1024 / BN, 2048 / BM), blk, 0, stream>>>(
        AOp, w_out, out, Bb * QL, Hh, Hh);
}

// Round 2
// 328.874 us; speedup vs baseline: 4.0117x; 4.0117x over previous
//
#include <hip/hip_runtime.h>

// Problem constants (CompactCrossAttention)
#define Bb   2
#define QL   1024
#define KL   4096
#define Hh   1024
#define NH   16
#define HD   64

typedef unsigned short u16;
typedef __attribute__((ext_vector_type(8))) short bf16x8;   // MFMA A/B frag (4 VGPRs)
typedef __attribute__((ext_vector_type(8))) unsigned short usv8;
typedef __attribute__((ext_vector_type(4))) float f32x4;    // MFMA C/D frag

__device__ __forceinline__ u16 f2bf(float f) {
    union { float f; unsigned int u; } v; v.f = f;
    unsigned int r = (v.u + 0x7FFFu + ((v.u >> 16) & 1u)) >> 16;
    return (u16)r;
}

__device__ __forceinline__ void gload16(const void* g, void* l) {
    __builtin_amdgcn_global_load_lds(
        (const __attribute__((address_space(1))) void*)g,
        (__attribute__((address_space(3))) void*)l, 16, 0, 0);
}

// ---------------------------------------------------------------------------
// fp32 -> bf16 elementwise cast (vectorized, grid-stride)
// ---------------------------------------------------------------------------
__global__ __launch_bounds__(256) void cast_bf16(const float* __restrict__ in,
                                                 u16* __restrict__ out, int n) {
    for (int i = (blockIdx.x * 256 + threadIdx.x) * 4; i < n; i += gridDim.x * 256 * 4) {
        float4 v = *reinterpret_cast<const float4*>(in + i);
        ushort4 o;
        o.x = f2bf(v.x); o.y = f2bf(v.y); o.z = f2bf(v.z); o.w = f2bf(v.w);
        *reinterpret_cast<ushort4*>(out + i) = o;
    }
}

// ---------------------------------------------------------------------------
// fp32 [R][C] -> bf16 [C][R] transpose+cast (weights). R,C multiples of 64.
// ---------------------------------------------------------------------------
__global__ __launch_bounds__(256) void wtrans(const float* __restrict__ in,
                                              u16* __restrict__ out, int R, int C) {
    __shared__ float T[64][65];
    const int nc = C >> 6;
    const int c0 = (blockIdx.x % nc) * 64;
    const int r0 = (blockIdx.x / nc) * 64;
    const int t  = threadIdx.x;
    const int tx = t & 15, ty = t >> 4;
#pragma unroll
    for (int p = 0; p < 4; ++p) {
        const int r = ty + p * 16;
        float4 v = *reinterpret_cast<const float4*>(in + (size_t)(r0 + r) * C + c0 + tx * 4);
        T[r][tx * 4 + 0] = v.x; T[r][tx * 4 + 1] = v.y;
        T[r][tx * 4 + 2] = v.z; T[r][tx * 4 + 3] = v.w;
    }
    __syncthreads();
#pragma unroll
    for (int p = 0; p < 4; ++p) {
        const int c = ty + p * 16;
        ushort4 o;
        o.x = f2bf(T[tx * 4 + 0][c]); o.y = f2bf(T[tx * 4 + 1][c]);
        o.z = f2bf(T[tx * 4 + 2][c]); o.w = f2bf(T[tx * 4 + 3][c]);
        *reinterpret_cast<ushort4*>(out + (size_t)(c0 + c) * R + r0 + tx * 4) = o;
    }
}

// ---------------------------------------------------------------------------
// V transpose: KVb bf16 [B*KL][2048] (V = cols 1024+) -> VT bf16 [B*NH*64][KL]
// One 64x64 tile per block.
// ---------------------------------------------------------------------------
__global__ __launch_bounds__(256) void vtrans(const u16* __restrict__ kv,
                                              u16* __restrict__ vt) {
    __shared__ u16 T[64][72];
    const int kt = blockIdx.x & 63;          // k-tile
    const int bh = blockIdx.x >> 6;          // 0..31
    const int b  = bh >> 4, h = bh & 15;
    const int t  = threadIdx.x;
    const int rr = t >> 3;                   // 0..31
    const int cc = (t & 7) * 8;              // 0..56
#pragma unroll
    for (int p = 0; p < 2; ++p) {
        const int k = rr + p * 32;
        *reinterpret_cast<usv8*>(&T[k][cc]) = *reinterpret_cast<const usv8*>(
            kv + (size_t)(b * KL + kt * 64 + k) * 2048 + 1024 + h * 64 + cc);
    }
    __syncthreads();
#pragma unroll
    for (int p = 0; p < 2; ++p) {
        const int d = rr + p * 32;
        usv8 o;
#pragma unroll
        for (int i = 0; i < 8; ++i) o[i] = T[cc + i][d];
        *reinterpret_cast<usv8*>(vt + (size_t)(bh * 64 + d) * KL + kt * 64 + cc) = o;
    }
}

// ---------------------------------------------------------------------------
// bf16 MFMA GEMM: C[M,N] = scale * (A[M,K] @ Bt[N,K]^T), m97-style structure.
// 128x128 tile, BK=64, 256 threads (4 waves, 2x2), 16x16x32 MFMA, acc 4x4.
// ---------------------------------------------------------------------------
template <bool BF16_OUT>
__global__ __launch_bounds__(256) void gemm_bf16(const u16* __restrict__ A,
                                                 const u16* __restrict__ Bt,
                                                 void* __restrict__ Cv,
                                                 int M, int N, int K, float scale) {
    __shared__ u16 As[128 * 64];   // linear [row][k], row stride 128 B
    __shared__ u16 Bs[128 * 64];

    const int tid  = threadIdx.x;
    const int lane = tid & 63;
    const int w    = tid >> 6;
    const int wr   = w >> 1, wc = w & 1;
    const int row0 = blockIdx.y * 128;
    const int col0 = blockIdx.x * 128;

    f32x4 acc[4][4];
#pragma unroll
    for (int m = 0; m < 4; ++m)
#pragma unroll
        for (int n = 0; n < 4; ++n) acc[m][n] = (f32x4){0.f, 0.f, 0.f, 0.f};

    const int lrow = lane >> 3;          // 0..7
    const int lcol = (lane & 7) * 8;     // element offset within 64-wide k row

    for (int k0 = 0; k0 < K; k0 += 64) {
        __syncthreads();
        // stage A,B tiles: 4 passes each wave, dest linear (wave-uniform base)
#pragma unroll
        for (int p = 0; p < 4; ++p) {
            const int base = w * 512 + p * 2048;          // elements
            const int row  = (base >> 6) + lrow;          // w*8 + p*32 + lane/8
            gload16(A + (size_t)(row0 + row) * K + k0 + lcol, &As[base]);
        }
#pragma unroll
        for (int p = 0; p < 4; ++p) {
            const int base = w * 512 + p * 2048;
            const int row  = (base >> 6) + lrow;
            gload16(Bt + (size_t)(col0 + row) * K + k0 + lcol, &Bs[base]);
        }
        __syncthreads();   // compiler drains vmcnt before barrier

#pragma unroll
        for (int kk = 0; kk < 2; ++kk) {
            bf16x8 af[4], bfr[4];
            const int koff = kk * 32 + (lane >> 4) * 8;
#pragma unroll
            for (int m = 0; m < 4; ++m)
                af[m] = *reinterpret_cast<const bf16x8*>(
                    &As[(wr * 64 + m * 16 + (lane & 15)) * 64 + koff]);
#pragma unroll
            for (int n = 0; n < 4; ++n)
                bfr[n] = *reinterpret_cast<const bf16x8*>(
                    &Bs[(wc * 64 + n * 16 + (lane & 15)) * 64 + koff]);
#pragma unroll
            for (int m = 0; m < 4; ++m)
#pragma unroll
                for (int n = 0; n < 4; ++n)
                    acc[m][n] = __builtin_amdgcn_mfma_f32_16x16x32_bf16(
                        af[m], bfr[n], acc[m][n], 0, 0, 0);
        }
    }

    // epilogue: C[row][col], row = (lane>>4)*4 + r, col = lane&15 per frag
#pragma unroll
    for (int m = 0; m < 4; ++m) {
#pragma unroll
        for (int n = 0; n < 4; ++n) {
            const int gc = col0 + wc * 64 + n * 16 + (lane & 15);
#pragma unroll
            for (int r = 0; r < 4; ++r) {
                const int gr = row0 + wr * 64 + m * 16 + (lane >> 4) * 4 + r;
                const float val = acc[m][n][r] * scale;
                if (BF16_OUT)
                    ((u16*)Cv)[(size_t)gr * N + gc] = f2bf(val);
                else
                    ((float*)Cv)[(size_t)gr * N + gc] = val;
            }
        }
    }
}

// ---------------------------------------------------------------------------
// bf16 MFMA flash attention.
// Grid: B*NH*(QL/64) = 512 blocks, 256 threads (4 waves). Wave w: q rows
// w*16..w*16+15 of this block's 64-row q tile. Loop over KL in 64-key tiles.
// Q pre-scaled by 1/8 in the Q-projection epilogue.
// ---------------------------------------------------------------------------
__global__ __launch_bounds__(256) void attn_mfma(const u16* __restrict__ Qb,   // [B*QL][1024]
                                                 const u16* __restrict__ KVb,  // [B*KL][2048]
                                                 const u16* __restrict__ VT,   // [B*NH*64][KL]
                                                 u16* __restrict__ AO) {       // [B*QL][1024]
    __shared__ u16 Ks[64][72];       // [k][d]  (= B^T layout for QK^T)
    __shared__ u16 Vs[64][72];       // [d][k]  (= B^T layout for PV)
    __shared__ u16 Ps[4][16][72];    // per-wave P tile [q][k]

    const int bid  = blockIdx.x;
    const int qb   = bid & 15;
    const int h    = (bid >> 4) & 15;
    const int b    = bid >> 8;
    const int tid  = threadIdx.x;
    const int lane = tid & 63;
    const int w    = tid >> 6;
    const int q0   = qb * 64;
    const int bh   = b * NH + h;

    // Q A-frags in registers (row = lane&15, k-group = lane>>4)
    bf16x8 qa[2];
    {
        const u16* qsrc = Qb + (size_t)(b * QL + q0 + w * 16 + (lane & 15)) * Hh
                          + h * HD + (lane >> 4) * 8;
        qa[0] = *reinterpret_cast<const bf16x8*>(qsrc);
        qa[1] = *reinterpret_cast<const bf16x8*>(qsrc + 32);
    }

    float m_i[4], l_i[4];
    f32x4 acc_o[4];
#pragma unroll
    for (int r = 0; r < 4; ++r) { m_i[r] = -1e30f; l_i[r] = 0.f; }
#pragma unroll
    for (int n = 0; n < 4; ++n) acc_o[n] = (f32x4){0.f, 0.f, 0.f, 0.f};

    const int rr = tid >> 3;          // staging row 0..31
    const int cc = (tid & 7) * 8;     // staging col chunk

    for (int k0 = 0; k0 < KL; k0 += 64) {
        __syncthreads();
        // stage K tile [k][d] and V^T tile [d][k]
#pragma unroll
        for (int p = 0; p < 2; ++p) {
            const int k = rr + p * 32;
            *reinterpret_cast<usv8*>(&Ks[k][cc]) = *reinterpret_cast<const usv8*>(
                KVb + (size_t)(b * KL + k0 + k) * 2048 + h * HD + cc);
            *reinterpret_cast<usv8*>(&Vs[k][cc]) = *reinterpret_cast<const usv8*>(
                VT + (size_t)(bh * 64 + k) * KL + k0 + cc);
        }
        __syncthreads();

        // QK^T: S[16q x 64k] per wave (scores already scaled via Q)
        f32x4 s[4];
#pragma unroll
        for (int n = 0; n < 4; ++n) {
            const u16* kp = &Ks[n * 16 + (lane & 15)][(lane >> 4) * 8];
            bf16x8 kf0 = *reinterpret_cast<const bf16x8*>(kp);
            bf16x8 kf1 = *reinterpret_cast<const bf16x8*>(kp + 32);
            f32x4 z = (f32x4){0.f, 0.f, 0.f, 0.f};
            z = __builtin_amdgcn_mfma_f32_16x16x32_bf16(qa[0], kf0, z, 0, 0, 0);
            z = __builtin_amdgcn_mfma_f32_16x16x32_bf16(qa[1], kf1, z, 0, 0, 0);
            s[n] = z;
        }

        // online softmax; rows owned: (lane>>4)*4 + r; key-lanes = lane&15
        float al[4];
#pragma unroll
        for (int r = 0; r < 4; ++r) {
            float mx = fmaxf(fmaxf(s[0][r], s[1][r]), fmaxf(s[2][r], s[3][r]));
            mx = fmaxf(mx, __shfl_xor(mx, 1));
            mx = fmaxf(mx, __shfl_xor(mx, 2));
            mx = fmaxf(mx, __shfl_xor(mx, 4));
            mx = fmaxf(mx, __shfl_xor(mx, 8));
            const float mnew = fmaxf(m_i[r], mx);
            al[r] = __expf(m_i[r] - mnew);
            m_i[r] = mnew;
            float sum = 0.f;
#pragma unroll
            for (int n = 0; n < 4; ++n) {
                const float p = __expf(s[n][r] - mnew);
                sum += p;
                Ps[w][(lane >> 4) * 4 + r][n * 16 + (lane & 15)] = f2bf(p);
            }
            sum += __shfl_xor(sum, 1);
            sum += __shfl_xor(sum, 2);
            sum += __shfl_xor(sum, 4);
            sum += __shfl_xor(sum, 8);
            l_i[r] = l_i[r] * al[r] + sum;
        }
#pragma unroll
        for (int n = 0; n < 4; ++n) {
            f32x4 t = acc_o[n];
            t[0] *= al[0]; t[1] *= al[1]; t[2] *= al[2]; t[3] *= al[3];
            acc_o[n] = t;
        }

        __syncthreads();   // make P visible for cross-lane A-frag reads

        // PV: O[16q x 64d] += P[16q x 64k] @ V[64k x 64d]
#pragma unroll
        for (int kf = 0; kf < 2; ++kf) {
            bf16x8 pf = *reinterpret_cast<const bf16x8*>(
                &Ps[w][lane & 15][kf * 32 + (lane >> 4) * 8]);
#pragma unroll
            for (int n = 0; n < 4; ++n) {
                bf16x8 vf = *reinterpret_cast<const bf16x8*>(
                    &Vs[n * 16 + (lane & 15)][kf * 32 + (lane >> 4) * 8]);
                acc_o[n] = __builtin_amdgcn_mfma_f32_16x16x32_bf16(
                    pf, vf, acc_o[n], 0, 0, 0);
            }
        }
    }

    // epilogue: normalize, write bf16 AO in [B,QL,H] layout
    float inv[4];
#pragma unroll
    for (int r = 0; r < 4; ++r) inv[r] = 1.f / l_i[r];
#pragma unroll
    for (int n = 0; n < 4; ++n) {
#pragma unroll
        for (int r = 0; r < 4; ++r) {
            const int gr = b * QL + q0 + w * 16 + (lane >> 4) * 4 + r;
            const int gc = h * HD + n * 16 + (lane & 15);
            AO[(size_t)gr * Hh + gc] = f2bf(acc_o[n][r] * inv[r]);
        }
    }
}

// ---------------------------------------------------------------------------
// Launch
// ---------------------------------------------------------------------------
extern "C" void kernel_launch(void* const* d_in, const int* in_sizes, int n_in,
                              void* d_out, int out_size, void* d_ws, size_t ws_size,
                              hipStream_t stream) {
    const float* query     = (const float*)d_in[0];
    const float* key_value = (const float*)d_in[1];
    const float* w_q       = (const float*)d_in[2];
    const float* w_kv      = (const float*)d_in[3];
    const float* w_out     = (const float*)d_in[4];
    float* out = (float*)d_out;

    char* ws = (char*)d_ws;
    const size_t MB = 1024 * 1024;
    u16* KVb   = (u16*)(ws);                 // 32 MB  [8192][2048]
    u16* Qb    = (u16*)(ws + 32 * MB);       //  4 MB  [2048][1024]
    u16* qbfAO = (u16*)(ws + 36 * MB);       //  4 MB  qbf (steps 1-4) then AO (step 7+)
    u16* kvbVT = (u16*)(ws + 40 * MB);       // 16 MB  kvbf (steps 2-5) then VT (step 6+)
    u16* wqT   = (u16*)(ws + 56 * MB);       //  2 MB  [1024][1024]
    u16* wkvT  = (u16*)(ws + 58 * MB);       //  4 MB  [2048][1024]
    u16* woutT = (u16*)(ws + 62 * MB);       //  2 MB  [1024][1024]

    dim3 blk(256);

    // 1-2) cast activations to bf16
    cast_bf16<<<2048, blk, 0, stream>>>(query, qbfAO, Bb * QL * Hh);
    cast_bf16<<<2048, blk, 0, stream>>>(key_value, kvbVT, Bb * KL * Hh);

    // 3-5) transpose+cast weights to [N][K] bf16
    wtrans<<<256, blk, 0, stream>>>(w_q, wqT, Hh, Hh);
    wtrans<<<512, blk, 0, stream>>>(w_kv, wkvT, Hh, 2 * Hh);
    wtrans<<<256, blk, 0, stream>>>(w_out, woutT, Hh, Hh);

    // 6) Qb = 0.125 * (query @ w_q)   [2048][1024] bf16
    gemm_bf16<true><<<dim3(1024 / 128, 2048 / 128), blk, 0, stream>>>(
        qbfAO, wqT, Qb, Bb * QL, Hh, Hh, 0.125f);

    // 7) KVb = key_value @ w_kv       [8192][2048] bf16
    gemm_bf16<true><<<dim3(2048 / 128, 8192 / 128), blk, 0, stream>>>(
        kvbVT, wkvT, KVb, Bb * KL, 2 * Hh, Hh, 1.0f);

    // 8) VT = V^T per head            [32*64][4096] bf16 (overwrites kvbf)
    vtrans<<<2048, blk, 0, stream>>>(KVb, kvbVT);

    // 9) attention -> AO bf16 [2048][1024] (overwrites qbf)
    attn_mfma<<<512, blk, 0, stream>>>(Qb, KVb, kvbVT, qbfAO);

    // 10) out = AO @ w_out            [2048][1024] fp32
    gemm_bf16<false><<<dim3(1024 / 128, 2048 / 128), blk, 0, stream>>>(
        qbfAO, woutT, out, Bb * QL, Hh, Hh, 1.0f);
}

// Round 3
// 264.390 us; speedup vs baseline: 4.9902x; 1.2439x over previous
//
#include <hip/hip_runtime.h>

// Problem constants (CompactCrossAttention)
#define Bb   2
#define QL   1024
#define KL   4096
#define Hh   1024
#define NH   16
#define HD   64

#define KSPLIT 2
#define CHUNK  (KL / KSPLIT)   // 2048 keys per block
#define NT     (CHUNK / 64)    // 32 tiles

typedef unsigned short u16;
typedef __attribute__((ext_vector_type(8))) short bf16x8;   // MFMA A/B frag (4 VGPRs)
typedef __attribute__((ext_vector_type(8))) unsigned short usv8;
typedef __attribute__((ext_vector_type(4))) float f32x4;    // MFMA C/D frag

__device__ __forceinline__ u16 f2bf(float f) {
    union { float f; unsigned int u; } v; v.f = f;
    unsigned int r = (v.u + 0x7FFFu + ((v.u >> 16) & 1u)) >> 16;
    return (u16)r;
}

__device__ __forceinline__ void gload16(const void* g, void* l) {
    __builtin_amdgcn_global_load_lds(
        (const __attribute__((address_space(1))) void*)g,
        (__attribute__((address_space(3))) void*)l, 16, 0, 0);
}

// ---------------------------------------------------------------------------
// fp32 -> bf16 elementwise cast
// ---------------------------------------------------------------------------
__global__ __launch_bounds__(256) void cast_bf16(const float* __restrict__ in,
                                                 u16* __restrict__ out, int n) {
    for (int i = (blockIdx.x * 256 + threadIdx.x) * 4; i < n; i += gridDim.x * 256 * 4) {
        float4 v = *reinterpret_cast<const float4*>(in + i);
        ushort4 o;
        o.x = f2bf(v.x); o.y = f2bf(v.y); o.z = f2bf(v.z); o.w = f2bf(v.w);
        *reinterpret_cast<ushort4*>(out + i) = o;
    }
}

// ---------------------------------------------------------------------------
// fp32 [R][C] -> bf16 [C][R] transpose+cast (weights)
// ---------------------------------------------------------------------------
__global__ __launch_bounds__(256) void wtrans(const float* __restrict__ in,
                                              u16* __restrict__ out, int R, int C) {
    __shared__ float T[64][65];
    const int nc = C >> 6;
    const int c0 = (blockIdx.x % nc) * 64;
    const int r0 = (blockIdx.x / nc) * 64;
    const int t  = threadIdx.x;
    const int tx = t & 15, ty = t >> 4;
#pragma unroll
    for (int p = 0; p < 4; ++p) {
        const int r = ty + p * 16;
        float4 v = *reinterpret_cast<const float4*>(in + (size_t)(r0 + r) * C + c0 + tx * 4);
        T[r][tx * 4 + 0] = v.x; T[r][tx * 4 + 1] = v.y;
        T[r][tx * 4 + 2] = v.z; T[r][tx * 4 + 3] = v.w;
    }
    __syncthreads();
#pragma unroll
    for (int p = 0; p < 4; ++p) {
        const int c = ty + p * 16;
        ushort4 o;
        o.x = f2bf(T[tx * 4 + 0][c]); o.y = f2bf(T[tx * 4 + 1][c]);
        o.z = f2bf(T[tx * 4 + 2][c]); o.w = f2bf(T[tx * 4 + 3][c]);
        *reinterpret_cast<ushort4*>(out + (size_t)(c0 + c) * R + r0 + tx * 4) = o;
    }
}

// ---------------------------------------------------------------------------
// V transpose: Vbuf bf16 [B*KL][1024] -> VT bf16 [B*NH*64][KL]
// ---------------------------------------------------------------------------
__global__ __launch_bounds__(256) void vtrans(const u16* __restrict__ v,
                                              u16* __restrict__ vt) {
    __shared__ u16 T[64][72];
    const int kt = blockIdx.x & 63;
    const int bh = blockIdx.x >> 6;
    const int b  = bh >> 4, h = bh & 15;
    const int t  = threadIdx.x;
    const int rr = t >> 3;
    const int cc = (t & 7) * 8;
#pragma unroll
    for (int p = 0; p < 2; ++p) {
        const int k = rr + p * 32;
        *reinterpret_cast<usv8*>(&T[k][cc]) = *reinterpret_cast<const usv8*>(
            v + (size_t)(b * KL + kt * 64 + k) * 1024 + h * 64 + cc);
    }
    __syncthreads();
#pragma unroll
    for (int p = 0; p < 2; ++p) {
        const int d = rr + p * 32;
        usv8 o;
#pragma unroll
        for (int i = 0; i < 8; ++i) o[i] = T[cc + i][d];
        *reinterpret_cast<usv8*>(vt + (size_t)(bh * 64 + d) * KL + kt * 64 + cc) = o;
    }
}

// ---------------------------------------------------------------------------
// bf16 MFMA GEMM: C = scale * (A[M,K] @ Bt[N,K]^T), m97-style.
// Columns < NA go to CvA (row width NA); columns >= NA go to CvB (width N-NA).
// ---------------------------------------------------------------------------
template <bool BF16_OUT>
__global__ __launch_bounds__(256) void gemm_bf16(const u16* __restrict__ A,
                                                 const u16* __restrict__ Bt,
                                                 void* __restrict__ CvA,
                                                 void* __restrict__ CvB,
                                                 int M, int N, int K, int NA,
                                                 float scale) {
    __shared__ u16 As[128 * 64];
    __shared__ u16 Bs[128 * 64];

    const int tid  = threadIdx.x;
    const int lane = tid & 63;
    const int w    = tid >> 6;
    const int wr   = w >> 1, wc = w & 1;
    const int row0 = blockIdx.y * 128;
    const int col0 = blockIdx.x * 128;

    f32x4 acc[4][4];
#pragma unroll
    for (int m = 0; m < 4; ++m)
#pragma unroll
        for (int n = 0; n < 4; ++n) acc[m][n] = (f32x4){0.f, 0.f, 0.f, 0.f};

    const int lrow = lane >> 3;
    const int lcol = (lane & 7) * 8;

    for (int k0 = 0; k0 < K; k0 += 64) {
        __syncthreads();
#pragma unroll
        for (int p = 0; p < 4; ++p) {
            const int base = w * 512 + p * 2048;
            const int row  = (base >> 6) + lrow;
            gload16(A + (size_t)(row0 + row) * K + k0 + lcol, &As[base]);
        }
#pragma unroll
        for (int p = 0; p < 4; ++p) {
            const int base = w * 512 + p * 2048;
            const int row  = (base >> 6) + lrow;
            gload16(Bt + (size_t)(col0 + row) * K + k0 + lcol, &Bs[base]);
        }
        __syncthreads();

#pragma unroll
        for (int kk = 0; kk < 2; ++kk) {
            bf16x8 af[4], bfr[4];
            const int koff = kk * 32 + (lane >> 4) * 8;
#pragma unroll
            for (int m = 0; m < 4; ++m)
                af[m] = *reinterpret_cast<const bf16x8*>(
                    &As[(wr * 64 + m * 16 + (lane & 15)) * 64 + koff]);
#pragma unroll
            for (int n = 0; n < 4; ++n)
                bfr[n] = *reinterpret_cast<const bf16x8*>(
                    &Bs[(wc * 64 + n * 16 + (lane & 15)) * 64 + koff]);
#pragma unroll
            for (int m = 0; m < 4; ++m)
#pragma unroll
                for (int n = 0; n < 4; ++n)
                    acc[m][n] = __builtin_amdgcn_mfma_f32_16x16x32_bf16(
                        af[m], bfr[n], acc[m][n], 0, 0, 0);
        }
    }

#pragma unroll
    for (int m = 0; m < 4; ++m) {
#pragma unroll
        for (int n = 0; n < 4; ++n) {
            const int gc = col0 + wc * 64 + n * 16 + (lane & 15);
            const bool inA = gc < NA;
            const int  cw  = inA ? NA : (N - NA);
            const int  cc2 = inA ? gc : gc - NA;
            void* base = inA ? CvA : CvB;
#pragma unroll
            for (int r = 0; r < 4; ++r) {
                const int gr = row0 + wr * 64 + m * 16 + (lane >> 4) * 4 + r;
                const float val = acc[m][n][r] * scale;
                if (BF16_OUT)
                    ((u16*)base)[(size_t)gr * cw + cc2] = f2bf(val);
                else
                    ((float*)base)[(size_t)gr * cw + cc2] = val;
            }
        }
    }
}

// ---------------------------------------------------------------------------
// Split-K bf16 MFMA flash attention.
// Grid: KSPLIT * B * NH * (QL/64) = 1024 blocks, 256 threads (4 waves).
// Each block: 64 q-rows x one 2048-key chunk. Register-prefetched staging,
// 2 barriers/tile, intra-wave P via lgkmcnt wait. Writes unnormalized O (f32)
// plus per-row (m, l) for the combine pass.
// ---------------------------------------------------------------------------
struct TileRegs { usv8 k0, k1, v0, v1; };

__global__ __launch_bounds__(256) void attn_mfma(const u16* __restrict__ Qb,   // [B*QL][1024]
                                                 const u16* __restrict__ Kb,   // [B*KL][1024]
                                                 const u16* __restrict__ VT,   // [B*NH*64][KL]
                                                 float* __restrict__ Op,       // [KSPLIT][B*QL][1024]
                                                 float* __restrict__ m_ws,     // [KSPLIT*B*NH*QL]
                                                 float* __restrict__ l_ws) {
    __shared__ u16 Ks[64][72];       // [k][d]
    __shared__ u16 Vs[64][72];       // [d][k]  (tile of V^T)
    __shared__ u16 Ps[4][16][72];    // per-wave P tile [q][k]

    const int bid  = blockIdx.x;
    const int qb   = bid & 15;
    const int h    = (bid >> 4) & 15;
    const int b    = (bid >> 8) & 1;
    const int c    = bid >> 9;
    const int tid  = threadIdx.x;
    const int lane = tid & 63;
    const int w    = tid >> 6;
    const int q0   = qb * 64;
    const int bh   = b * NH + h;
    const int k0g  = c * CHUNK;

    // Q A-frags in registers
    bf16x8 qa[2];
    {
        const u16* qsrc = Qb + (size_t)(b * QL + q0 + w * 16 + (lane & 15)) * Hh
                          + h * HD + (lane >> 4) * 8;
        qa[0] = *reinterpret_cast<const bf16x8*>(qsrc);
        qa[1] = *reinterpret_cast<const bf16x8*>(qsrc + 32);
    }

    float m_i[4], l_i[4];
    f32x4 acc_o[4];
#pragma unroll
    for (int r = 0; r < 4; ++r) { m_i[r] = -1e30f; l_i[r] = 0.f; }
#pragma unroll
    for (int n = 0; n < 4; ++n) acc_o[n] = (f32x4){0.f, 0.f, 0.f, 0.f};

    const int rr = tid >> 3;          // 0..31
    const int cc = (tid & 7) * 8;     // 0..56

    const u16* kp = Kb + (size_t)(b * KL + k0g + rr) * Hh + h * HD + cc;
    const u16* vp = VT + (size_t)(bh * 64 + rr) * KL + k0g + cc;

    TileRegs rA, rB;
    rA.k0 = *reinterpret_cast<const usv8*>(kp);
    rA.k1 = *reinterpret_cast<const usv8*>(kp + (size_t)32 * Hh);
    rA.v0 = *reinterpret_cast<const usv8*>(vp);
    rA.v1 = *reinterpret_cast<const usv8*>(vp + (size_t)32 * KL);

    auto body = [&](TileRegs& cur, TileRegs& nxt, int t, bool pf) {
        __syncthreads();   // all waves done reading LDS from previous tile
        *reinterpret_cast<usv8*>(&Ks[rr][cc])      = cur.k0;
        *reinterpret_cast<usv8*>(&Ks[rr + 32][cc]) = cur.k1;
        *reinterpret_cast<usv8*>(&Vs[rr][cc])      = cur.v0;
        *reinterpret_cast<usv8*>(&Vs[rr + 32][cc]) = cur.v1;
        if (pf) {   // issue next tile's loads; they fly during this tile's compute
            const size_t ko = (size_t)(t + 1) * 64;
            nxt.k0 = *reinterpret_cast<const usv8*>(kp + ko * Hh);
            nxt.k1 = *reinterpret_cast<const usv8*>(kp + (ko + 32) * Hh);
            nxt.v0 = *reinterpret_cast<const usv8*>(vp + ko);
            nxt.v1 = *reinterpret_cast<const usv8*>(vp + ko + (size_t)32 * KL);
        }
        __syncthreads();   // LDS tile visible

        // QK^T: S[16q x 64k] per wave (scores pre-scaled via Q)
        f32x4 s[4];
#pragma unroll
        for (int n = 0; n < 4; ++n) {
            const u16* kfp = &Ks[n * 16 + (lane & 15)][(lane >> 4) * 8];
            bf16x8 kf0 = *reinterpret_cast<const bf16x8*>(kfp);
            bf16x8 kf1 = *reinterpret_cast<const bf16x8*>(kfp + 32);
            f32x4 z = (f32x4){0.f, 0.f, 0.f, 0.f};
            z = __builtin_amdgcn_mfma_f32_16x16x32_bf16(qa[0], kf0, z, 0, 0, 0);
            z = __builtin_amdgcn_mfma_f32_16x16x32_bf16(qa[1], kf1, z, 0, 0, 0);
            s[n] = z;
        }

        // online softmax (rows (lane>>4)*4+r; 16 key-lanes = lane&15 group)
        float al[4];
#pragma unroll
        for (int r = 0; r < 4; ++r) {
            float mx = fmaxf(fmaxf(s[0][r], s[1][r]), fmaxf(s[2][r], s[3][r]));
            mx = fmaxf(mx, __shfl_xor(mx, 1));
            mx = fmaxf(mx, __shfl_xor(mx, 2));
            mx = fmaxf(mx, __shfl_xor(mx, 4));
            mx = fmaxf(mx, __shfl_xor(mx, 8));
            const float mnew = fmaxf(m_i[r], mx);
            al[r] = __expf(m_i[r] - mnew);
            m_i[r] = mnew;
            float sum = 0.f;
#pragma unroll
            for (int n = 0; n < 4; ++n) {
                const float p = __expf(s[n][r] - mnew);
                sum += p;
                Ps[w][(lane >> 4) * 4 + r][n * 16 + (lane & 15)] = f2bf(p);
            }
            sum += __shfl_xor(sum, 1);
            sum += __shfl_xor(sum, 2);
            sum += __shfl_xor(sum, 4);
            sum += __shfl_xor(sum, 8);
            l_i[r] = l_i[r] * al[r] + sum;
        }
#pragma unroll
        for (int n = 0; n < 4; ++n) {
            f32x4 tt = acc_o[n];
            tt[0] *= al[0]; tt[1] *= al[1]; tt[2] *= al[2]; tt[3] *= al[3];
            acc_o[n] = tt;
        }

        // intra-wave P visibility: LDS write->read within the same wave only
        asm volatile("s_waitcnt lgkmcnt(0)" ::: "memory");
        __builtin_amdgcn_sched_barrier(0);

        // PV: O[16q x 64d] += P[16q x 64k] @ V[64k x 64d]
#pragma unroll
        for (int kf = 0; kf < 2; ++kf) {
            bf16x8 pf2 = *reinterpret_cast<const bf16x8*>(
                &Ps[w][lane & 15][kf * 32 + (lane >> 4) * 8]);
#pragma unroll
            for (int n = 0; n < 4; ++n) {
                bf16x8 vf = *reinterpret_cast<const bf16x8*>(
                    &Vs[n * 16 + (lane & 15)][kf * 32 + (lane >> 4) * 8]);
                acc_o[n] = __builtin_amdgcn_mfma_f32_16x16x32_bf16(
                    pf2, vf, acc_o[n], 0, 0, 0);
            }
        }
    };

    for (int t = 0; t < NT; t += 2) {
        body(rA, rB, t, true);
        body(rB, rA, t + 1, t + 2 < NT);
    }

    // epilogue: unnormalized O (f32) + per-row m,l
    float* opc = Op + (size_t)c * ((size_t)Bb * QL * Hh);
#pragma unroll
    for (int n = 0; n < 4; ++n) {
#pragma unroll
        for (int r = 0; r < 4; ++r) {
            const int gr = b * QL + q0 + w * 16 + (lane >> 4) * 4 + r;
            const int gc = h * HD + n * 16 + (lane & 15);
            opc[(size_t)gr * Hh + gc] = acc_o[n][r];
        }
    }
    if ((lane & 15) == 0) {
#pragma unroll
        for (int r = 0; r < 4; ++r) {
            const int q = q0 + w * 16 + (lane >> 4) * 4 + r;
            const int idx = ((c * Bb + b) * NH + h) * QL + q;
            m_ws[idx] = m_i[r];
            l_ws[idx] = l_i[r];
        }
    }
}

// ---------------------------------------------------------------------------
// Combine KSPLIT=2 partial attention results -> bf16 AO [B*QL][1024]
// ---------------------------------------------------------------------------
__global__ __launch_bounds__(256) void attn_combine(const float* __restrict__ Op,
                                                    const float* __restrict__ m_ws,
                                                    const float* __restrict__ l_ws,
                                                    u16* __restrict__ AO) {
    const int id  = blockIdx.x * 256 + threadIdx.x;
    const int e0  = id * 4;
    const int row = e0 >> 10;
    const int col = e0 & 1023;
    const int b   = row >> 10;
    const int q   = row & 1023;
    const int hh  = col >> 6;
    const int i0  = ((0 * Bb + b) * NH + hh) * QL + q;
    const int i1  = ((1 * Bb + b) * NH + hh) * QL + q;
    const float m0 = m_ws[i0], m1 = m_ws[i1];
    const float l0 = l_ws[i0], l1 = l_ws[i1];
    const float ms = fmaxf(m0, m1);
    const float w0 = __expf(m0 - ms), w1 = __expf(m1 - ms);
    const float inv = 1.f / (l0 * w0 + l1 * w1);
    const size_t off = (size_t)row * 1024 + col;
    float4 o0 = *reinterpret_cast<const float4*>(Op + off);
    float4 o1 = *reinterpret_cast<const float4*>(Op + (size_t)Bb * QL * Hh + off);
    ushort4 o;
    o.x = f2bf((o0.x * w0 + o1.x * w1) * inv);
    o.y = f2bf((o0.y * w0 + o1.y * w1) * inv);
    o.z = f2bf((o0.z * w0 + o1.z * w1) * inv);
    o.w = f2bf((o0.w * w0 + o1.w * w1) * inv);
    *reinterpret_cast<ushort4*>(AO + off) = o;
}

// ---------------------------------------------------------------------------
// Launch.  Workspace map (64 MB, overlays exploit liveness):
//   0-16  Kbuf  (KV gemm -> attn)
//  16-32  Vbuf  (KV gemm -> vtrans)   then Opart (attn -> combine)
//  32-48  kvbf  (cast -> KV gemm)     then VT    (vtrans -> attn)
//  48-52  Qb    (Q gemm -> attn)
//  52-56  wkvT  (wtrans -> KV gemm)   then AO    (combine -> out gemm)
//  56-60  qbf   (cast -> Q gemm)      then m_ws/l_ws (attn -> combine)
//  60-62  wqT   (wtrans -> Q gemm)
//  62-64  woutT (wtrans -> out gemm)
// ---------------------------------------------------------------------------
extern "C" void kernel_launch(void* const* d_in, const int* in_sizes, int n_in,
                              void* d_out, int out_size, void* d_ws, size_t ws_size,
                              hipStream_t stream) {
    const float* query     = (const float*)d_in[0];
    const float* key_value = (const float*)d_in[1];
    const float* w_q       = (const float*)d_in[2];
    const float* w_kv      = (const float*)d_in[3];
    const float* w_out     = (const float*)d_in[4];
    float* out = (float*)d_out;

    char* ws = (char*)d_ws;
    const size_t MB = 1024 * 1024;
    u16*   Kbuf  = (u16*)(ws);
    u16*   Vbuf  = (u16*)(ws + 16 * MB);
    float* Opart = (float*)(ws + 16 * MB);
    u16*   kvbf  = (u16*)(ws + 32 * MB);
    u16*   VT    = (u16*)(ws + 32 * MB);
    u16*   Qb    = (u16*)(ws + 48 * MB);
    u16*   wkvT  = (u16*)(ws + 52 * MB);
    u16*   AO    = (u16*)(ws + 52 * MB);
    u16*   qbf   = (u16*)(ws + 56 * MB);
    float* m_wsp = (float*)(ws + 56 * MB);
    float* l_wsp = (float*)(ws + 56 * MB + 256 * 1024);
    u16*   wqT   = (u16*)(ws + 60 * MB);
    u16*   woutT = (u16*)(ws + 62 * MB);

    dim3 blk(256);

    // casts + weight transposes
    cast_bf16<<<2048, blk, 0, stream>>>(query, qbf, Bb * QL * Hh);
    cast_bf16<<<2048, blk, 0, stream>>>(key_value, kvbf, Bb * KL * Hh);
    wtrans<<<256, blk, 0, stream>>>(w_q, wqT, Hh, Hh);
    wtrans<<<512, blk, 0, stream>>>(w_kv, wkvT, Hh, 2 * Hh);
    wtrans<<<256, blk, 0, stream>>>(w_out, woutT, Hh, Hh);

    // Qb = 0.125 * (query @ w_q)
    gemm_bf16<true><<<dim3(8, 16), blk, 0, stream>>>(
        qbf, wqT, Qb, Qb, Bb * QL, Hh, Hh, Hh, 0.125f);

    // K/V projection, split outputs: Kbuf [8192][1024], Vbuf [8192][1024]
    gemm_bf16<true><<<dim3(16, 64), blk, 0, stream>>>(
        kvbf, wkvT, Kbuf, Vbuf, Bb * KL, 2 * Hh, Hh, Hh, 1.0f);

    // VT = V^T per head  [32*64][4096]   (overwrites kvbf)
    vtrans<<<2048, blk, 0, stream>>>(Vbuf, VT);

    // split-K attention -> Opart/m/l    (overwrites Vbuf, qbf)
    attn_mfma<<<dim3(KSPLIT * 512), blk, 0, stream>>>(
        Qb, Kbuf, VT, Opart, m_wsp, l_wsp);

    // combine -> AO bf16                (overwrites wkvT)
    attn_combine<<<2048, blk, 0, stream>>>(Opart, m_wsp, l_wsp, AO);

    // out = AO @ w_out  (fp32)
    gemm_bf16<false><<<dim3(8, 16), blk, 0, stream>>>(
        AO, woutT, out, out, Bb * QL, Hh, Hh, Hh, 1.0f);
}

// Round 4
// 225.110 us; speedup vs baseline: 5.8609x; 1.1745x over previous
//
#include <hip/hip_runtime.h>

// Problem constants (CompactCrossAttention)
#define Bb   2
#define QL   1024
#define KL   4096
#define Hh   1024
#define NH   16
#define HD   64

#define KSPLIT 2
#define CHUNK  (KL / KSPLIT)   // 2048 keys per block
#define NT     (CHUNK / 64)    // 32 tiles

typedef unsigned short u16;
typedef __attribute__((ext_vector_type(8))) short bf16x8;   // MFMA A/B frag (4 VGPRs)
typedef __attribute__((ext_vector_type(8))) unsigned short usv8;
typedef __attribute__((ext_vector_type(4))) float f32x4;    // MFMA C/D frag

#define QSCALE 0.1803368801111204f   // 0.125 * log2(e): scores in log2 domain

__device__ __forceinline__ u16 f2bf(float f) {
    union { float f; unsigned int u; } v; v.f = f;
    unsigned int r = (v.u + 0x7FFFu + ((v.u >> 16) & 1u)) >> 16;
    return (u16)r;
}

__device__ __forceinline__ unsigned int cvt_pk_bf16(float lo, float hi) {
    unsigned int r;
    asm("v_cvt_pk_bf16_f32 %0, %1, %2" : "=v"(r) : "v"(lo), "v"(hi));
    return r;   // low16 = bf16(lo), high16 = bf16(hi)
}

__device__ __forceinline__ void gload16(const void* g, void* l) {
    __builtin_amdgcn_global_load_lds(
        (const __attribute__((address_space(1))) void*)g,
        (__attribute__((address_space(3))) void*)l, 16, 0, 0);
}

// ---------------------------------------------------------------------------
// fp32 -> bf16 elementwise cast
// ---------------------------------------------------------------------------
__global__ __launch_bounds__(256) void cast_bf16(const float* __restrict__ in,
                                                 u16* __restrict__ out, int n) {
    for (int i = (blockIdx.x * 256 + threadIdx.x) * 4; i < n; i += gridDim.x * 256 * 4) {
        float4 v = *reinterpret_cast<const float4*>(in + i);
        ushort4 o;
        o.x = f2bf(v.x); o.y = f2bf(v.y); o.z = f2bf(v.z); o.w = f2bf(v.w);
        *reinterpret_cast<ushort4*>(out + i) = o;
    }
}

// ---------------------------------------------------------------------------
// fp32 [R][C] -> bf16 [C][R] transpose+cast (weights)
// ---------------------------------------------------------------------------
__global__ __launch_bounds__(256) void wtrans(const float* __restrict__ in,
                                              u16* __restrict__ out, int R, int C) {
    __shared__ float T[64][65];
    const int nc = C >> 6;
    const int c0 = (blockIdx.x % nc) * 64;
    const int r0 = (blockIdx.x / nc) * 64;
    const int t  = threadIdx.x;
    const int tx = t & 15, ty = t >> 4;
#pragma unroll
    for (int p = 0; p < 4; ++p) {
        const int r = ty + p * 16;
        float4 v = *reinterpret_cast<const float4*>(in + (size_t)(r0 + r) * C + c0 + tx * 4);
        T[r][tx * 4 + 0] = v.x; T[r][tx * 4 + 1] = v.y;
        T[r][tx * 4 + 2] = v.z; T[r][tx * 4 + 3] = v.w;
    }
    __syncthreads();
#pragma unroll
    for (int p = 0; p < 4; ++p) {
        const int c = ty + p * 16;
        ushort4 o;
        o.x = f2bf(T[tx * 4 + 0][c]); o.y = f2bf(T[tx * 4 + 1][c]);
        o.z = f2bf(T[tx * 4 + 2][c]); o.w = f2bf(T[tx * 4 + 3][c]);
        *reinterpret_cast<ushort4*>(out + (size_t)(c0 + c) * R + r0 + tx * 4) = o;
    }
}

// ---------------------------------------------------------------------------
// V transpose: Vbuf bf16 [B*KL][1024] -> VT bf16 [B*NH*64][KL]
// ---------------------------------------------------------------------------
__global__ __launch_bounds__(256) void vtrans(const u16* __restrict__ v,
                                              u16* __restrict__ vt) {
    __shared__ u16 T[64][72];
    const int kt = blockIdx.x & 63;
    const int bh = blockIdx.x >> 6;
    const int b  = bh >> 4, h = bh & 15;
    const int t  = threadIdx.x;
    const int rr = t >> 3;
    const int cc = (t & 7) * 8;
#pragma unroll
    for (int p = 0; p < 2; ++p) {
        const int k = rr + p * 32;
        *reinterpret_cast<usv8*>(&T[k][cc]) = *reinterpret_cast<const usv8*>(
            v + (size_t)(b * KL + kt * 64 + k) * 1024 + h * 64 + cc);
    }
    __syncthreads();
#pragma unroll
    for (int p = 0; p < 2; ++p) {
        const int d = rr + p * 32;
        usv8 o;
#pragma unroll
        for (int i = 0; i < 8; ++i) o[i] = T[cc + i][d];
        *reinterpret_cast<usv8*>(vt + (size_t)(bh * 64 + d) * KL + kt * 64 + cc) = o;
    }
}

// ---------------------------------------------------------------------------
// bf16 MFMA GEMM: C = scale * (A[M,K] @ Bt[N,K]^T), m97-style, XCD-swizzled.
// Columns < NA go to CvA (row width NA); columns >= NA go to CvB (width N-NA).
// ---------------------------------------------------------------------------
template <bool BF16_OUT>
__global__ __launch_bounds__(256) void gemm_bf16(const u16* __restrict__ A,
                                                 const u16* __restrict__ Bt,
                                                 void* __restrict__ CvA,
                                                 void* __restrict__ CvB,
                                                 int M, int N, int K, int NA,
                                                 float scale) {
    __shared__ u16 As[128 * 64];
    __shared__ u16 Bs[128 * 64];

    // XCD-aware swizzle (nwg % 8 == 0 for all launches here)
    const int nwg = gridDim.x * gridDim.y;
    const int id  = blockIdx.y * gridDim.x + blockIdx.x;
    const int sw  = (id & 7) * (nwg >> 3) + (id >> 3);
    const int bx  = sw % gridDim.x;
    const int by  = sw / gridDim.x;

    const int tid  = threadIdx.x;
    const int lane = tid & 63;
    const int w    = tid >> 6;
    const int wr   = w >> 1, wc = w & 1;
    const int row0 = by * 128;
    const int col0 = bx * 128;

    f32x4 acc[4][4];
#pragma unroll
    for (int m = 0; m < 4; ++m)
#pragma unroll
        for (int n = 0; n < 4; ++n) acc[m][n] = (f32x4){0.f, 0.f, 0.f, 0.f};

    const int lrow = lane >> 3;
    const int lcol = (lane & 7) * 8;

    for (int k0 = 0; k0 < K; k0 += 64) {
        __syncthreads();
#pragma unroll
        for (int p = 0; p < 4; ++p) {
            const int base = w * 512 + p * 2048;
            const int row  = (base >> 6) + lrow;
            gload16(A + (size_t)(row0 + row) * K + k0 + lcol, &As[base]);
        }
#pragma unroll
        for (int p = 0; p < 4; ++p) {
            const int base = w * 512 + p * 2048;
            const int row  = (base >> 6) + lrow;
            gload16(Bt + (size_t)(col0 + row) * K + k0 + lcol, &Bs[base]);
        }
        __syncthreads();

#pragma unroll
        for (int kk = 0; kk < 2; ++kk) {
            bf16x8 af[4], bfr[4];
            const int koff = kk * 32 + (lane >> 4) * 8;
#pragma unroll
            for (int m = 0; m < 4; ++m)
                af[m] = *reinterpret_cast<const bf16x8*>(
                    &As[(wr * 64 + m * 16 + (lane & 15)) * 64 + koff]);
#pragma unroll
            for (int n = 0; n < 4; ++n)
                bfr[n] = *reinterpret_cast<const bf16x8*>(
                    &Bs[(wc * 64 + n * 16 + (lane & 15)) * 64 + koff]);
#pragma unroll
            for (int m = 0; m < 4; ++m)
#pragma unroll
                for (int n = 0; n < 4; ++n)
                    acc[m][n] = __builtin_amdgcn_mfma_f32_16x16x32_bf16(
                        af[m], bfr[n], acc[m][n], 0, 0, 0);
        }
    }

#pragma unroll
    for (int m = 0; m < 4; ++m) {
#pragma unroll
        for (int n = 0; n < 4; ++n) {
            const int gc = col0 + wc * 64 + n * 16 + (lane & 15);
            const bool inA = gc < NA;
            const int  cw  = inA ? NA : (N - NA);
            const int  cc2 = inA ? gc : gc - NA;
            void* base = inA ? CvA : CvB;
#pragma unroll
            for (int r = 0; r < 4; ++r) {
                const int gr = row0 + wr * 64 + m * 16 + (lane >> 4) * 4 + r;
                const float val = acc[m][n][r] * scale;
                if (BF16_OUT)
                    ((u16*)base)[(size_t)gr * cw + cc2] = f2bf(val);
                else
                    ((float*)base)[(size_t)gr * cw + cc2] = val;
            }
        }
    }
}

// ---------------------------------------------------------------------------
// Split-K bf16 MFMA flash attention, swapped-operand QK^T (S^T layout).
// Each lane owns ONE q-row (q = lane&15): row reductions are 15-op in-lane
// trees + 2 shfl_xor; P packed via v_cvt_pk + 4x ds_write_b64; PV computed
// as mfma(V^T, P^T) so O comes out [d][q] and stats stay lane-local.
// Scores are in log2 domain (Q pre-scaled by 0.125*log2e) -> exp2.
// ---------------------------------------------------------------------------
struct TileRegs { usv8 k0, k1, v0, v1; };

__global__ __launch_bounds__(256) void attn_mfma(const u16* __restrict__ Qb,   // [B*QL][1024]
                                                 const u16* __restrict__ Kb,   // [B*KL][1024]
                                                 const u16* __restrict__ VT,   // [B*NH*64][KL]
                                                 float* __restrict__ Op,       // [KSPLIT][B*QL][1024]
                                                 float* __restrict__ m_ws,     // [KSPLIT*B*NH*QL]
                                                 float* __restrict__ l_ws) {
    __shared__ u16 Ks[64][72];       // [k][d]
    __shared__ u16 Vs[64][72];       // [d][k]  (tile of V^T)
    __shared__ u16 Ps[4][16][72];    // per-wave P tile [q][k]

    // XCD swizzle: 16 consecutive orig-ids share one K/V chunk -> per-XCD L2
    const int bid0 = blockIdx.x;
    const int bid  = (bid0 & 7) * 128 + (bid0 >> 3);
    const int qb   = bid & 15;
    const int h    = (bid >> 4) & 15;
    const int b    = (bid >> 8) & 1;
    const int c    = bid >> 9;
    const int tid  = threadIdx.x;
    const int lane = tid & 63;
    const int w    = tid >> 6;
    const int q    = lane & 15;       // this lane's q-row (within wave's 16)
    const int g    = lane >> 4;       // lane group 0..3
    const int q0   = qb * 64;
    const int bh   = b * NH + h;
    const int k0g  = c * CHUNK;

    // Q B-frags in registers: qa[j](lane, e) = Q[q][d = j*32 + g*8 + e]
    bf16x8 qa[2];
    {
        const u16* qsrc = Qb + (size_t)(b * QL + q0 + w * 16 + q) * Hh
                          + h * HD + g * 8;
        qa[0] = *reinterpret_cast<const bf16x8*>(qsrc);
        qa[1] = *reinterpret_cast<const bf16x8*>(qsrc + 32);
    }

    float m_i = -1e30f, l_i = 0.f;
    f32x4 acc_o[4];   // acc_o[n][r] = O[d = n*16 + g*4 + r][q]
#pragma unroll
    for (int n = 0; n < 4; ++n) acc_o[n] = (f32x4){0.f, 0.f, 0.f, 0.f};

    const int rr = tid >> 3;          // staging row 0..31
    const int cc = (tid & 7) * 8;     // staging col chunk

    const u16* kp = Kb + (size_t)(b * KL + k0g + rr) * Hh + h * HD + cc;
    const u16* vp = VT + (size_t)(bh * 64 + rr) * KL + k0g + cc;

    TileRegs rA, rB;
    rA.k0 = *reinterpret_cast<const usv8*>(kp);
    rA.k1 = *reinterpret_cast<const usv8*>(kp + (size_t)32 * Hh);
    rA.v0 = *reinterpret_cast<const usv8*>(vp);
    rA.v1 = *reinterpret_cast<const usv8*>(vp + (size_t)32 * KL);

    auto body = [&](TileRegs& cur, TileRegs& nxt, int t, bool pf) {
        __syncthreads();   // all waves done reading LDS from previous tile
        *reinterpret_cast<usv8*>(&Ks[rr][cc])      = cur.k0;
        *reinterpret_cast<usv8*>(&Ks[rr + 32][cc]) = cur.k1;
        *reinterpret_cast<usv8*>(&Vs[rr][cc])      = cur.v0;
        *reinterpret_cast<usv8*>(&Vs[rr + 32][cc]) = cur.v1;
        if (pf) {   // next tile's loads fly during this tile's compute
            const size_t ko = (size_t)(t + 1) * 64;
            nxt.k0 = *reinterpret_cast<const usv8*>(kp + ko * Hh);
            nxt.k1 = *reinterpret_cast<const usv8*>(kp + (ko + 32) * Hh);
            nxt.v0 = *reinterpret_cast<const usv8*>(vp + ko);
            nxt.v1 = *reinterpret_cast<const usv8*>(vp + ko + (size_t)32 * KL);
        }
        __syncthreads();   // LDS tile visible

        // QK^T swapped: s[n] = S^T chunk; s[n][r] = S[key=n*16+g*4+r][q]
        f32x4 s[4];
#pragma unroll
        for (int n = 0; n < 4; ++n) {
            const u16* kfp = &Ks[n * 16 + q][g * 8];
            bf16x8 kf0 = *reinterpret_cast<const bf16x8*>(kfp);
            bf16x8 kf1 = *reinterpret_cast<const bf16x8*>(kfp + 32);
            f32x4 z = (f32x4){0.f, 0.f, 0.f, 0.f};
            z = __builtin_amdgcn_mfma_f32_16x16x32_bf16(kf0, qa[0], z, 0, 0, 0);
            z = __builtin_amdgcn_mfma_f32_16x16x32_bf16(kf1, qa[1], z, 0, 0, 0);
            s[n] = z;
        }

        // online softmax: all 16 scores belong to row q -> in-lane tree + 2 shfl
        float t0 = fmaxf(fmaxf(s[0][0], s[0][1]), fmaxf(s[0][2], s[0][3]));
        float t1 = fmaxf(fmaxf(s[1][0], s[1][1]), fmaxf(s[1][2], s[1][3]));
        float t2 = fmaxf(fmaxf(s[2][0], s[2][1]), fmaxf(s[2][2], s[2][3]));
        float t3 = fmaxf(fmaxf(s[3][0], s[3][1]), fmaxf(s[3][2], s[3][3]));
        float mloc = fmaxf(fmaxf(t0, t1), fmaxf(t2, t3));
        mloc = fmaxf(mloc, __shfl_xor(mloc, 16));
        mloc = fmaxf(mloc, __shfl_xor(mloc, 32));
        const float mnew = fmaxf(m_i, mloc);
        const float al = exp2f(m_i - mnew);
        m_i = mnew;

        float p[4][4];
#pragma unroll
        for (int n = 0; n < 4; ++n)
#pragma unroll
            for (int r = 0; r < 4; ++r) p[n][r] = exp2f(s[n][r] - mnew);
        float u0 = (p[0][0] + p[0][1]) + (p[0][2] + p[0][3]);
        float u1 = (p[1][0] + p[1][1]) + (p[1][2] + p[1][3]);
        float u2 = (p[2][0] + p[2][1]) + (p[2][2] + p[2][3]);
        float u3 = (p[3][0] + p[3][1]) + (p[3][2] + p[3][3]);
        float sum = (u0 + u1) + (u2 + u3);
        sum += __shfl_xor(sum, 16);
        sum += __shfl_xor(sum, 32);
        l_i = l_i * al + sum;

        // pack P -> bf16 pairs, write P[q][k] rows (4x ds_write_b64)
#pragma unroll
        for (int n = 0; n < 4; ++n) {
            uint2 pk2;
            pk2.x = cvt_pk_bf16(p[n][0], p[n][1]);
            pk2.y = cvt_pk_bf16(p[n][2], p[n][3]);
            *reinterpret_cast<uint2*>(&Ps[w][q][n * 16 + g * 4]) = pk2;
        }

        // rescale O
#pragma unroll
        for (int n = 0; n < 4; ++n) {
            f32x4 tt = acc_o[n];
            tt[0] *= al; tt[1] *= al; tt[2] *= al; tt[3] *= al;
            acc_o[n] = tt;
        }

        // intra-wave P visibility (per-wave Ps): drain LDS, fence scheduler
        asm volatile("s_waitcnt lgkmcnt(0)" ::: "memory");
        __builtin_amdgcn_sched_barrier(0);

        // PV swapped: acc_o[n] += mfma(V^T rows, P^T cols)
#pragma unroll
        for (int kf = 0; kf < 2; ++kf) {
            bf16x8 pfr = *reinterpret_cast<const bf16x8*>(
                &Ps[w][q][kf * 32 + g * 8]);
#pragma unroll
            for (int n = 0; n < 4; ++n) {
                bf16x8 vf = *reinterpret_cast<const bf16x8*>(
                    &Vs[n * 16 + q][kf * 32 + g * 8]);
                acc_o[n] = __builtin_amdgcn_mfma_f32_16x16x32_bf16(
                    vf, pfr, acc_o[n], 0, 0, 0);
            }
        }
    };

    for (int t = 0; t < NT; t += 2) {
        body(rA, rB, t, true);
        body(rB, rA, t + 1, t + 2 < NT);
    }

    // epilogue: unnormalized O (f32, float4 stores) + per-row m,l
    float* opc = Op + (size_t)c * ((size_t)Bb * QL * Hh)
                 + (size_t)(b * QL + q0 + w * 16 + q) * Hh + h * HD;
#pragma unroll
    for (int n = 0; n < 4; ++n) {
        float4 v = make_float4(acc_o[n][0], acc_o[n][1], acc_o[n][2], acc_o[n][3]);
        *reinterpret_cast<float4*>(opc + n * 16 + g * 4) = v;
    }
    if (g == 0) {
        const int idx = ((c * Bb + b) * NH + h) * QL + q0 + w * 16 + q;
        m_ws[idx] = m_i;
        l_ws[idx] = l_i;
    }
}

// ---------------------------------------------------------------------------
// Combine KSPLIT=2 partials -> bf16 AO [B*QL][1024].  (log2-domain maxima)
// ---------------------------------------------------------------------------
__global__ __launch_bounds__(256) void attn_combine(const float* __restrict__ Op,
                                                    const float* __restrict__ m_ws,
                                                    const float* __restrict__ l_ws,
                                                    u16* __restrict__ AO) {
    const int id  = blockIdx.x * 256 + threadIdx.x;
    const int e0  = id * 4;
    const int row = e0 >> 10;
    const int col = e0 & 1023;
    const int b   = row >> 10;
    const int q   = row & 1023;
    const int hh  = col >> 6;
    const int i0  = ((0 * Bb + b) * NH + hh) * QL + q;
    const int i1  = ((1 * Bb + b) * NH + hh) * QL + q;
    const float m0 = m_ws[i0], m1 = m_ws[i1];
    const float l0 = l_ws[i0], l1 = l_ws[i1];
    const float ms = fmaxf(m0, m1);
    const float w0 = exp2f(m0 - ms), w1 = exp2f(m1 - ms);
    const float inv = 1.f / (l0 * w0 + l1 * w1);
    const size_t off = (size_t)row * 1024 + col;
    float4 o0 = *reinterpret_cast<const float4*>(Op + off);
    float4 o1 = *reinterpret_cast<const float4*>(Op + (size_t)Bb * QL * Hh + off);
    ushort4 o;
    o.x = f2bf((o0.x * w0 + o1.x * w1) * inv);
    o.y = f2bf((o0.y * w0 + o1.y * w1) * inv);
    o.z = f2bf((o0.z * w0 + o1.z * w1) * inv);
    o.w = f2bf((o0.w * w0 + o1.w * w1) * inv);
    *reinterpret_cast<ushort4*>(AO + off) = o;
}

// ---------------------------------------------------------------------------
// Launch.  Workspace map (64 MB, overlays exploit liveness):
//   0-16  Kbuf   16-32 Vbuf/Opart   32-48 kvbf/VT   48-52 Qb
//  52-56  wkvT/AO   56-60 qbf/m_ws,l_ws   60-62 wqT   62-64 woutT
// ---------------------------------------------------------------------------
extern "C" void kernel_launch(void* const* d_in, const int* in_sizes, int n_in,
                              void* d_out, int out_size, void* d_ws, size_t ws_size,
                              hipStream_t stream) {
    const float* query     = (const float*)d_in[0];
    const float* key_value = (const float*)d_in[1];
    const float* w_q       = (const float*)d_in[2];
    const float* w_kv      = (const float*)d_in[3];
    const float* w_out     = (const float*)d_in[4];
    float* out = (float*)d_out;

    char* ws = (char*)d_ws;
    const size_t MB = 1024 * 1024;
    u16*   Kbuf  = (u16*)(ws);
    u16*   Vbuf  = (u16*)(ws + 16 * MB);
    float* Opart = (float*)(ws + 16 * MB);
    u16*   kvbf  = (u16*)(ws + 32 * MB);
    u16*   VT    = (u16*)(ws + 32 * MB);
    u16*   Qb    = (u16*)(ws + 48 * MB);
    u16*   wkvT  = (u16*)(ws + 52 * MB);
    u16*   AO    = (u16*)(ws + 52 * MB);
    u16*   qbf   = (u16*)(ws + 56 * MB);
    float* m_wsp = (float*)(ws + 56 * MB);
    float* l_wsp = (float*)(ws + 56 * MB + 256 * 1024);
    u16*   wqT   = (u16*)(ws + 60 * MB);
    u16*   woutT = (u16*)(ws + 62 * MB);

    dim3 blk(256);

    cast_bf16<<<2048, blk, 0, stream>>>(query, qbf, Bb * QL * Hh);
    cast_bf16<<<2048, blk, 0, stream>>>(key_value, kvbf, Bb * KL * Hh);
    wtrans<<<256, blk, 0, stream>>>(w_q, wqT, Hh, Hh);
    wtrans<<<512, blk, 0, stream>>>(w_kv, wkvT, Hh, 2 * Hh);
    wtrans<<<256, blk, 0, stream>>>(w_out, woutT, Hh, Hh);

    // Qb = (0.125*log2e) * (query @ w_q)  -> scores in log2 domain
    gemm_bf16<true><<<dim3(8, 16), blk, 0, stream>>>(
        qbf, wqT, Qb, Qb, Bb * QL, Hh, Hh, Hh, QSCALE);

    // K/V projection, split outputs: Kbuf [8192][1024], Vbuf [8192][1024]
    gemm_bf16<true><<<dim3(16, 64), blk, 0, stream>>>(
        kvbf, wkvT, Kbuf, Vbuf, Bb * KL, 2 * Hh, Hh, Hh, 1.0f);

    // VT = V^T per head  [32*64][4096]   (overwrites kvbf)
    vtrans<<<2048, blk, 0, stream>>>(Vbuf, VT);

    // split-K attention -> Opart/m/l    (overwrites Vbuf, qbf)
    attn_mfma<<<dim3(KSPLIT * 512), blk, 0, stream>>>(
        Qb, Kbuf, VT, Opart, m_wsp, l_wsp);

    // combine -> AO bf16                (overwrites wkvT)
    attn_combine<<<2048, blk, 0, stream>>>(Opart, m_wsp, l_wsp, AO);

    // out = AO @ w_out  (fp32)
    gemm_bf16<false><<<dim3(8, 16), blk, 0, stream>>>(
        AO, woutT, out, out, Bb * QL, Hh, Hh, Hh, 1.0f);
}

// Round 5
// 213.039 us; speedup vs baseline: 6.1930x; 1.0567x over previous
//
#include <hip/hip_runtime.h>

// Problem constants (CompactCrossAttention)
#define Bb   2
#define QL   1024
#define KL   4096
#define Hh   1024
#define NH   16
#define HD   64

#define KSPLIT 2
#define CHUNK  (KL / KSPLIT)   // 2048 keys per block
#define NTT    (CHUNK / 64)    // 32 tiles of 64 keys

typedef unsigned short u16;
typedef __attribute__((ext_vector_type(8))) short bf16x8;   // MFMA A/B frag
typedef __attribute__((ext_vector_type(8))) unsigned short usv8;
typedef __attribute__((ext_vector_type(4))) float f32x4;    // MFMA C/D frag

#define QSCALE 0.1803368801111204f   // 0.125 * log2(e): scores in log2 domain
#define RTHR   11.0f                 // defer-max threshold (log2 units, ~8 nats)

__device__ __forceinline__ u16 f2bf(float f) {
    union { float f; unsigned int u; } v; v.f = f;
    unsigned int r = (v.u + 0x7FFFu + ((v.u >> 16) & 1u)) >> 16;
    return (u16)r;
}

__device__ __forceinline__ unsigned int cvt_pk_bf16(float lo, float hi) {
    unsigned int r;
    asm("v_cvt_pk_bf16_f32 %0, %1, %2" : "=v"(r) : "v"(lo), "v"(hi));
    return r;
}

__device__ __forceinline__ void gload16(const void* g, void* l) {
    __builtin_amdgcn_global_load_lds(
        (const __attribute__((address_space(1))) void*)g,
        (__attribute__((address_space(3))) void*)l, 16, 0, 0);
}

// ---------------------------------------------------------------------------
// fp32 -> bf16 elementwise cast
// ---------------------------------------------------------------------------
__global__ __launch_bounds__(256) void cast_bf16(const float* __restrict__ in,
                                                 u16* __restrict__ out, int n) {
    for (int i = (blockIdx.x * 256 + threadIdx.x) * 4; i < n; i += gridDim.x * 256 * 4) {
        float4 v = *reinterpret_cast<const float4*>(in + i);
        ushort4 o;
        o.x = f2bf(v.x); o.y = f2bf(v.y); o.z = f2bf(v.z); o.w = f2bf(v.w);
        *reinterpret_cast<ushort4*>(out + i) = o;
    }
}

// ---------------------------------------------------------------------------
// fp32 [R][C] -> bf16 [C][R] transpose+cast (weights)
// ---------------------------------------------------------------------------
__global__ __launch_bounds__(256) void wtrans(const float* __restrict__ in,
                                              u16* __restrict__ out, int R, int C) {
    __shared__ float T[64][65];
    const int nc = C >> 6;
    const int c0 = (blockIdx.x % nc) * 64;
    const int r0 = (blockIdx.x / nc) * 64;
    const int t  = threadIdx.x;
    const int tx = t & 15, ty = t >> 4;
#pragma unroll
    for (int p = 0; p < 4; ++p) {
        const int r = ty + p * 16;
        float4 v = *reinterpret_cast<const float4*>(in + (size_t)(r0 + r) * C + c0 + tx * 4);
        T[r][tx * 4 + 0] = v.x; T[r][tx * 4 + 1] = v.y;
        T[r][tx * 4 + 2] = v.z; T[r][tx * 4 + 3] = v.w;
    }
    __syncthreads();
#pragma unroll
    for (int p = 0; p < 4; ++p) {
        const int c = ty + p * 16;
        ushort4 o;
        o.x = f2bf(T[tx * 4 + 0][c]); o.y = f2bf(T[tx * 4 + 1][c]);
        o.z = f2bf(T[tx * 4 + 2][c]); o.w = f2bf(T[tx * 4 + 3][c]);
        *reinterpret_cast<ushort4*>(out + (size_t)(c0 + c) * R + r0 + tx * 4) = o;
    }
}

// ---------------------------------------------------------------------------
// ktrans: Kbuf [B*KL][1024] -> KT [bh][tile64][512 granules] where slot
// (k, pg) holds K[k][d-granule gl], gl = pg ^ (k&7). Tile blob = 8 KB,
// linear order == attn's swizzled LDS layout (gload_lds-ready).
// ---------------------------------------------------------------------------
__global__ __launch_bounds__(256) void ktrans(const u16* __restrict__ kb,
                                              u16* __restrict__ kt) {
    const int tg = blockIdx.x & 63;     // 64-key tile
    const int bh = blockIdx.x >> 6;     // 0..31
    const int b  = bh >> 4, h = bh & 15;
    const int t_ = threadIdx.x;
#pragma unroll
    for (int p = 0; p < 2; ++p) {
        const int og = p * 256 + t_;        // 0..511
        const int k  = og >> 3;
        const int pg = og & 7;
        const int gl = pg ^ (k & 7);
        usv8 v = *reinterpret_cast<const usv8*>(
            kb + (size_t)(b * KL + tg * 64 + k) * 1024 + h * 64 + gl * 8);
        *reinterpret_cast<usv8*>(kt + ((size_t)(bh * 64 + tg) * 512 + og) * 8) = v;
    }
}

// ---------------------------------------------------------------------------
// vtrans: Vbuf [B*KL][1024] -> VT2 [bh][tile64][512 granules] where slot
// (d, pg) holds V^T row d, key-granule g4 = pg ^ (d&7) (8 consecutive keys).
// ---------------------------------------------------------------------------
__global__ __launch_bounds__(256) void vtrans(const u16* __restrict__ vb,
                                              u16* __restrict__ vt) {
    __shared__ u16 T[64][72];
    const int tg = blockIdx.x & 63;
    const int bh = blockIdx.x >> 6;
    const int b  = bh >> 4, h = bh & 15;
    const int t_ = threadIdx.x;
#pragma unroll
    for (int p = 0; p < 2; ++p) {
        const int k = (t_ >> 3) + p * 32;
        *reinterpret_cast<usv8*>(&T[k][(t_ & 7) * 8]) =
            *reinterpret_cast<const usv8*>(
                vb + (size_t)(b * KL + tg * 64 + k) * 1024 + h * 64 + (t_ & 7) * 8);
    }
    __syncthreads();
#pragma unroll
    for (int p = 0; p < 2; ++p) {
        const int og = p * 256 + t_;        // 0..511
        const int d  = og >> 3;
        const int pg = og & 7;
        const int g4 = pg ^ (d & 7);
        usv8 o;
#pragma unroll
        for (int e = 0; e < 8; ++e) o[e] = T[g4 * 8 + e][d];
        *reinterpret_cast<usv8*>(vt + ((size_t)(bh * 64 + tg) * 512 + og) * 8) = o;
    }
}

// ---------------------------------------------------------------------------
// bf16 MFMA GEMM: C = scale * (A[M,K] @ Bt[N,K]^T), m97-style, XCD-swizzled.
// BMT = block M-tile (128 or 64). Columns < NA -> CvA, else CvB.
// ---------------------------------------------------------------------------
template <bool BF16_OUT, int BMT>
__global__ __launch_bounds__(256) void gemm_bf16(const u16* __restrict__ A,
                                                 const u16* __restrict__ Bt,
                                                 void* __restrict__ CvA,
                                                 void* __restrict__ CvB,
                                                 int M, int N, int K, int NA,
                                                 float scale) {
    __shared__ u16 As[BMT * 64];
    __shared__ u16 Bs[128 * 64];
    constexpr int MR = BMT / 32;        // acc rows: 4 or 2
    constexpr int AP = BMT / 32;        // A staging passes

    const int nwg = gridDim.x * gridDim.y;
    const int id  = blockIdx.y * gridDim.x + blockIdx.x;
    const int sw  = (id & 7) * (nwg >> 3) + (id >> 3);
    const int bx  = sw % gridDim.x;
    const int by  = sw / gridDim.x;

    const int tid  = threadIdx.x;
    const int lane = tid & 63;
    const int w    = tid >> 6;
    const int wr   = w >> 1, wc = w & 1;
    const int MROW = wr * (BMT / 2);
    const int row0 = by * BMT;
    const int col0 = bx * 128;

    f32x4 acc[MR][4];
#pragma unroll
    for (int m = 0; m < MR; ++m)
#pragma unroll
        for (int n = 0; n < 4; ++n) acc[m][n] = (f32x4){0.f, 0.f, 0.f, 0.f};

    const int lrow = lane >> 3;
    const int lcol = (lane & 7) * 8;

    for (int k0 = 0; k0 < K; k0 += 64) {
        __syncthreads();
#pragma unroll
        for (int p = 0; p < AP; ++p) {
            const int base = w * 512 + p * 2048;
            const int row  = (base >> 6) + lrow;
            gload16(A + (size_t)(row0 + row) * K + k0 + lcol, &As[base]);
        }
#pragma unroll
        for (int p = 0; p < 4; ++p) {
            const int base = w * 512 + p * 2048;
            const int row  = (base >> 6) + lrow;
            gload16(Bt + (size_t)(col0 + row) * K + k0 + lcol, &Bs[base]);
        }
        __syncthreads();

#pragma unroll
        for (int kk = 0; kk < 2; ++kk) {
            bf16x8 af[MR], bfr[4];
            const int koff = kk * 32 + (lane >> 4) * 8;
#pragma unroll
            for (int m = 0; m < MR; ++m)
                af[m] = *reinterpret_cast<const bf16x8*>(
                    &As[(MROW + m * 16 + (lane & 15)) * 64 + koff]);
#pragma unroll
            for (int n = 0; n < 4; ++n)
                bfr[n] = *reinterpret_cast<const bf16x8*>(
                    &Bs[(wc * 64 + n * 16 + (lane & 15)) * 64 + koff]);
#pragma unroll
            for (int m = 0; m < MR; ++m)
#pragma unroll
                for (int n = 0; n < 4; ++n)
                    acc[m][n] = __builtin_amdgcn_mfma_f32_16x16x32_bf16(
                        af[m], bfr[n], acc[m][n], 0, 0, 0);
        }
    }

#pragma unroll
    for (int m = 0; m < MR; ++m) {
#pragma unroll
        for (int n = 0; n < 4; ++n) {
            const int gc = col0 + wc * 64 + n * 16 + (lane & 15);
            const bool inA = gc < NA;
            const int  cw  = inA ? NA : (N - NA);
            const int  cc2 = inA ? gc : gc - NA;
            void* base = inA ? CvA : CvB;
#pragma unroll
            for (int r = 0; r < 4; ++r) {
                const int gr = row0 + MROW + m * 16 + (lane >> 4) * 4 + r;
                const float val = acc[m][n][r] * scale;
                if (BF16_OUT)
                    ((u16*)base)[(size_t)gr * cw + cc2] = f2bf(val);
                else
                    ((float*)base)[(size_t)gr * cw + cc2] = val;
            }
        }
    }
}

// ---------------------------------------------------------------------------
// Split-K bf16 MFMA flash attention. Swapped-operand QK^T, XOR-swizzled LDS
// (pre-swizzled in KT/VT2 global blobs), double-buffered tiles staged via
// global_load_lds with counted vmcnt (loads fly across raw s_barriers),
// defer-max online softmax in log2 domain, setprio around MFMA clusters.
// ---------------------------------------------------------------------------
__global__ __launch_bounds__(256, 4) void attn_mfma(const u16* __restrict__ Qb,  // [B*QL][1024]
                                                    const u16* __restrict__ KT,  // tile blobs
                                                    const u16* __restrict__ VT2, // tile blobs
                                                    float* __restrict__ Op,      // [KSPLIT][B*QL][1024]
                                                    float* __restrict__ m_ws,
                                                    float* __restrict__ l_ws) {
    __shared__ u16 Ks[2][64 * 64];   // [k][pg*8], pg = g ^ (k&7)
    __shared__ u16 Vs[2][64 * 64];   // [d][pg*8], pg = g ^ (d&7)
    __shared__ u16 Ps[4][16][64];    // per-wave P, row q, granule phys = g ^ (q&7)

    const int bid0 = blockIdx.x;
    const int bid  = (bid0 & 7) * 128 + (bid0 >> 3);   // XCD swizzle
    const int qb   = bid & 15;
    const int h    = (bid >> 4) & 15;
    const int b    = (bid >> 8) & 1;
    const int c    = bid >> 9;
    const int tid  = threadIdx.x;
    const int lane = tid & 63;
    const int w    = tid >> 6;
    const int q_l  = lane & 15;
    const int g    = lane >> 4;
    const int qs7  = q_l & 7;
    const int q0   = qb * 64;
    const int bh   = b * NH + h;

    // Q B-frags: qa[j](lane,e) = Q[q_l][d = j*32 + g*8 + e]
    bf16x8 qa0, qa1;
    {
        const u16* qsrc = Qb + (size_t)(b * QL + q0 + w * 16 + q_l) * Hh
                          + h * HD + g * 8;
        qa0 = *reinterpret_cast<const bf16x8*>(qsrc);
        qa1 = *reinterpret_cast<const bf16x8*>(qsrc + 32);
    }
    asm volatile("s_waitcnt vmcnt(0)" ::: "memory");   // qa resident before pipeline

    float m_i = -1e30f, l_i = 0.f;
    f32x4 acc_o[4];   // acc_o[n][r] = O[d = n*16 + g*4 + r][q_l]
#pragma unroll
    for (int n = 0; n < 4; ++n) acc_o[n] = (f32x4){0.f, 0.f, 0.f, 0.f};

    // tile blob bases (granule index *8 = u16 offset)
    const size_t tb0 = ((size_t)bh * 64 + c * NTT) * 512;

    auto issue4 = [&](int t, int bufi) {
        const size_t kb = (tb0 + (size_t)t * 512) * 8;
#pragma unroll
        for (int p = 0; p < 2; ++p) {
            gload16(KT + kb + (size_t)(p * 256 + w * 64 + lane) * 8,
                    &Ks[bufi][(p * 256 + w * 64) * 8]);
        }
#pragma unroll
        for (int p = 0; p < 2; ++p) {
            gload16(VT2 + kb + (size_t)(p * 256 + w * 64 + lane) * 8,
                    &Vs[bufi][(p * 256 + w * 64) * 8]);
        }
    };

    issue4(0, 0);

    for (int t = 0; t < NTT; ++t) {
        const int cur = t & 1;
        __builtin_amdgcn_s_barrier();          // prev compute done reading buf[cur^1]
        if (t + 1 < NTT) {
            issue4(t + 1, cur ^ 1);
            asm volatile("s_waitcnt vmcnt(4)" ::: "memory");   // buf[cur] landed; next 4 fly
        } else {
            asm volatile("s_waitcnt vmcnt(0)" ::: "memory");
        }
        __builtin_amdgcn_sched_barrier(0);
        __builtin_amdgcn_s_barrier();          // all waves' buf[cur] resident

        // QK^T swapped: s[n][r] = S[key = n*16 + g*4 + r][q_l]
        f32x4 s[4];
        __builtin_amdgcn_s_setprio(1);
#pragma unroll
        for (int n = 0; n < 4; ++n) {
            const int r_ = n * 16 + q_l;
            bf16x8 a0 = *reinterpret_cast<const bf16x8*>(
                &Ks[cur][r_ * 64 + (g ^ qs7) * 8]);
            bf16x8 a1 = *reinterpret_cast<const bf16x8*>(
                &Ks[cur][r_ * 64 + ((g + 4) ^ qs7) * 8]);
            f32x4 z = (f32x4){0.f, 0.f, 0.f, 0.f};
            z = __builtin_amdgcn_mfma_f32_16x16x32_bf16(a0, qa0, z, 0, 0, 0);
            z = __builtin_amdgcn_mfma_f32_16x16x32_bf16(a1, qa1, z, 0, 0, 0);
            s[n] = z;
        }
        __builtin_amdgcn_s_setprio(0);

        // online softmax (log2 domain), defer-max
        float t0 = fmaxf(fmaxf(s[0][0], s[0][1]), fmaxf(s[0][2], s[0][3]));
        float t1 = fmaxf(fmaxf(s[1][0], s[1][1]), fmaxf(s[1][2], s[1][3]));
        float t2 = fmaxf(fmaxf(s[2][0], s[2][1]), fmaxf(s[2][2], s[2][3]));
        float t3 = fmaxf(fmaxf(s[3][0], s[3][1]), fmaxf(s[3][2], s[3][3]));
        float mloc = fmaxf(fmaxf(t0, t1), fmaxf(t2, t3));
        mloc = fmaxf(mloc, __shfl_xor(mloc, 16));
        mloc = fmaxf(mloc, __shfl_xor(mloc, 32));
        if (__any(mloc > m_i + RTHR)) {
            const float mnew = fmaxf(m_i, mloc);
            const float al   = exp2f(m_i - mnew);
            m_i = mnew;
            l_i *= al;
#pragma unroll
            for (int n = 0; n < 4; ++n) {
                f32x4 tt = acc_o[n];
                tt[0] *= al; tt[1] *= al; tt[2] *= al; tt[3] *= al;
                acc_o[n] = tt;
            }
        }
#pragma unroll
        for (int n = 0; n < 4; ++n)
#pragma unroll
            for (int r = 0; r < 4; ++r) s[n][r] = exp2f(s[n][r] - m_i);
        float u0 = (s[0][0] + s[0][1]) + (s[0][2] + s[0][3]);
        float u1 = (s[1][0] + s[1][1]) + (s[1][2] + s[1][3]);
        float u2 = (s[2][0] + s[2][1]) + (s[2][2] + s[2][3]);
        float u3 = (s[3][0] + s[3][1]) + (s[3][2] + s[3][3]);
        float sum = (u0 + u1) + (u2 + u3);
        sum += __shfl_xor(sum, 16);
        sum += __shfl_xor(sum, 32);
        l_i += sum;

        // pack P -> bf16, swizzled b64 writes
#pragma unroll
        for (int n = 0; n < 4; ++n) {
            uint2 pk2;
            pk2.x = cvt_pk_bf16(s[n][0], s[n][1]);
            pk2.y = cvt_pk_bf16(s[n][2], s[n][3]);
            const int phys = (2 * n + (g >> 1)) ^ qs7;
            *reinterpret_cast<uint2*>(&Ps[w][q_l][phys * 8 + (g & 1) * 4]) = pk2;
        }
        asm volatile("s_waitcnt lgkmcnt(0)" ::: "memory");
        __builtin_amdgcn_sched_barrier(0);

        // PV swapped: acc_o[n] += mfma(V^T, P^T)
        __builtin_amdgcn_s_setprio(1);
#pragma unroll
        for (int kf = 0; kf < 2; ++kf) {
            const int phk = ((kf * 4 + g) ^ qs7) * 8;
            bf16x8 pfr = *reinterpret_cast<const bf16x8*>(&Ps[w][q_l][phk]);
#pragma unroll
            for (int n = 0; n < 4; ++n) {
                const int d_ = n * 16 + q_l;
                bf16x8 vf = *reinterpret_cast<const bf16x8*>(
                    &Vs[cur][d_ * 64 + phk]);
                acc_o[n] = __builtin_amdgcn_mfma_f32_16x16x32_bf16(
                    vf, pfr, acc_o[n], 0, 0, 0);
            }
        }
        __builtin_amdgcn_s_setprio(0);
    }

    // epilogue: unnormalized O (float4 stores) + per-row m,l
    float* opc = Op + (size_t)c * ((size_t)Bb * QL * Hh)
                 + (size_t)(b * QL + q0 + w * 16 + q_l) * Hh + h * HD;
#pragma unroll
    for (int n = 0; n < 4; ++n) {
        float4 v = make_float4(acc_o[n][0], acc_o[n][1], acc_o[n][2], acc_o[n][3]);
        *reinterpret_cast<float4*>(opc + n * 16 + g * 4) = v;
    }
    if (g == 0) {
        const int idx = ((c * Bb + b) * NH + h) * QL + q0 + w * 16 + q_l;
        m_ws[idx] = m_i;
        l_ws[idx] = l_i;
    }
}

// ---------------------------------------------------------------------------
// Combine KSPLIT=2 partials -> bf16 AO [B*QL][1024]  (log2-domain maxima)
// ---------------------------------------------------------------------------
__global__ __launch_bounds__(256) void attn_combine(const float* __restrict__ Op,
                                                    const float* __restrict__ m_ws,
                                                    const float* __restrict__ l_ws,
                                                    u16* __restrict__ AO) {
    const int id  = blockIdx.x * 256 + threadIdx.x;
    const int e0  = id * 4;
    const int row = e0 >> 10;
    const int col = e0 & 1023;
    const int b   = row >> 10;
    const int q   = row & 1023;
    const int hh  = col >> 6;
    const int i0  = ((0 * Bb + b) * NH + hh) * QL + q;
    const int i1  = ((1 * Bb + b) * NH + hh) * QL + q;
    const float m0 = m_ws[i0], m1 = m_ws[i1];
    const float l0 = l_ws[i0], l1 = l_ws[i1];
    const float ms = fmaxf(m0, m1);
    const float w0 = exp2f(m0 - ms), w1 = exp2f(m1 - ms);
    const float inv = 1.f / (l0 * w0 + l1 * w1);
    const size_t off = (size_t)row * 1024 + col;
    float4 o0 = *reinterpret_cast<const float4*>(Op + off);
    float4 o1 = *reinterpret_cast<const float4*>(Op + (size_t)Bb * QL * Hh + off);
    ushort4 o;
    o.x = f2bf((o0.x * w0 + o1.x * w1) * inv);
    o.y = f2bf((o0.y * w0 + o1.y * w1) * inv);
    o.z = f2bf((o0.z * w0 + o1.z * w1) * inv);
    o.w = f2bf((o0.w * w0 + o1.w * w1) * inv);
    *reinterpret_cast<ushort4*>(AO + off) = o;
}

// ---------------------------------------------------------------------------
// Launch.  Workspace (64 MB, liveness overlays):
//   0-16  Kbuf (KVgemm->ktrans)      then VT2  (vtrans->attn)
//  16-32  Vbuf (KVgemm->vtrans)      then Opart(attn->combine)
//  32-48  kvbf (cast->KVgemm)        then KT   (ktrans->attn)
//  48-52  Qb
//  52-56  qbf  (cast->Qgemm)         then AO   (combine->outgemm)
//  56-60  wkvT (wtrans->KVgemm)      then m_ws/l_ws (attn->combine)
//  60-62  wqT          62-64  woutT
// ---------------------------------------------------------------------------
extern "C" void kernel_launch(void* const* d_in, const int* in_sizes, int n_in,
                              void* d_out, int out_size, void* d_ws, size_t ws_size,
                              hipStream_t stream) {
    const float* query     = (const float*)d_in[0];
    const float* key_value = (const float*)d_in[1];
    const float* w_q       = (const float*)d_in[2];
    const float* w_kv      = (const float*)d_in[3];
    const float* w_out     = (const float*)d_in[4];
    float* out = (float*)d_out;

    char* ws = (char*)d_ws;
    const size_t MB = 1024 * 1024;
    u16*   Kbuf  = (u16*)(ws);
    u16*   VT2   = (u16*)(ws);
    u16*   Vbuf  = (u16*)(ws + 16 * MB);
    float* Opart = (float*)(ws + 16 * MB);
    u16*   kvbf  = (u16*)(ws + 32 * MB);
    u16*   KT    = (u16*)(ws + 32 * MB);
    u16*   Qb    = (u16*)(ws + 48 * MB);
    u16*   qbf   = (u16*)(ws + 52 * MB);
    u16*   AO    = (u16*)(ws + 52 * MB);
    u16*   wkvT  = (u16*)(ws + 56 * MB);
    float* m_wsp = (float*)(ws + 56 * MB);
    float* l_wsp = (float*)(ws + 56 * MB + 256 * 1024);
    u16*   wqT   = (u16*)(ws + 60 * MB);
    u16*   woutT = (u16*)(ws + 62 * MB);

    dim3 blk(256);

    cast_bf16<<<2048, blk, 0, stream>>>(query, qbf, Bb * QL * Hh);
    cast_bf16<<<2048, blk, 0, stream>>>(key_value, kvbf, Bb * KL * Hh);
    wtrans<<<256, blk, 0, stream>>>(w_q, wqT, Hh, Hh);
    wtrans<<<512, blk, 0, stream>>>(w_kv, wkvT, Hh, 2 * Hh);
    wtrans<<<256, blk, 0, stream>>>(w_out, woutT, Hh, Hh);

    // Qb = (0.125*log2e) * (query @ w_q)
    gemm_bf16<true, 64><<<dim3(8, 32), blk, 0, stream>>>(
        qbf, wqT, Qb, Qb, Bb * QL, Hh, Hh, Hh, QSCALE);

    // K/V projection -> Kbuf [8192][1024], Vbuf [8192][1024]
    gemm_bf16<true, 128><<<dim3(16, 64), blk, 0, stream>>>(
        kvbf, wkvT, Kbuf, Vbuf, Bb * KL, 2 * Hh, Hh, Hh, 1.0f);

    // pre-swizzled tile blobs (kvbf dead -> KT; then Kbuf dead -> VT2)
    ktrans<<<2048, blk, 0, stream>>>(Kbuf, KT);
    vtrans<<<2048, blk, 0, stream>>>(Vbuf, VT2);

    // split-K attention -> Opart (Vbuf dead) + m/l (wkvT dead)
    attn_mfma<<<dim3(KSPLIT * 512), blk, 0, stream>>>(
        Qb, KT, VT2, Opart, m_wsp, l_wsp);

    // combine -> AO (qbf dead)
    attn_combine<<<2048, blk, 0, stream>>>(Opart, m_wsp, l_wsp, AO);

    // out = AO @ w_out (fp32)
    gemm_bf16<false, 64><<<dim3(8, 32), blk, 0, stream>>>(
        AO, woutT, out, out, Bb * QL, Hh, Hh, Hh, 1.0f);
}

// Round 6
// 202.752 us; speedup vs baseline: 6.5072x; 1.0507x over previous
//
#include <hip/hip_runtime.h>

// Problem constants (CompactCrossAttention)
#define Bb   2
#define QL   1024
#define KL   4096
#define Hh   1024
#define NH   16
#define HD   64

#define KSPLIT 2
#define CHUNK  (KL / KSPLIT)   // 2048 keys per block
#define NTT    (CHUNK / 64)    // 32 tiles of 64 keys

typedef unsigned short u16;
typedef __attribute__((ext_vector_type(8))) short bf16x8;   // MFMA A/B frag
typedef __attribute__((ext_vector_type(8))) unsigned short usv8;
typedef __attribute__((ext_vector_type(4))) float f32x4;    // MFMA C/D frag

#define QSCALE 0.1803368801111204f   // 0.125 * log2(e): scores in log2 domain
#define RTHR   11.0f                 // defer-max threshold (log2 units)

__device__ __forceinline__ u16 f2bf(float f) {
    union { float f; unsigned int u; } v; v.f = f;
    unsigned int r = (v.u + 0x7FFFu + ((v.u >> 16) & 1u)) >> 16;
    return (u16)r;
}

__device__ __forceinline__ unsigned int cvt_pk_bf16(float lo, float hi) {
    unsigned int r;
    asm("v_cvt_pk_bf16_f32 %0, %1, %2" : "=v"(r) : "v"(lo), "v"(hi));
    return r;
}

__device__ __forceinline__ float max3f(float a, float b, float c) {
    float r;
    asm("v_max3_f32 %0, %1, %2, %3" : "=v"(r) : "v"(a), "v"(b), "v"(c));
    return r;
}

__device__ __forceinline__ void gload16(const void* g, void* l) {
    __builtin_amdgcn_global_load_lds(
        (const __attribute__((address_space(1))) void*)g,
        (__attribute__((address_space(3))) void*)l, 16, 0, 0);
}

// pack 8 fp32 -> 8 bf16 (uint4)
__device__ __forceinline__ uint4 pack8(const float4& f0, const float4& f1) {
    uint4 o;
    o.x = cvt_pk_bf16(f0.x, f0.y);
    o.y = cvt_pk_bf16(f0.z, f0.w);
    o.z = cvt_pk_bf16(f1.x, f1.y);
    o.w = cvt_pk_bf16(f1.z, f1.w);
    return o;
}

// ---------------------------------------------------------------------------
// All three weight transposes (fp32 [R][C] -> bf16 [C][R]) in ONE launch.
// grid 1024: [0,256) w_q, [256,768) w_kv, [768,1024) w_out.
// ---------------------------------------------------------------------------
__global__ __launch_bounds__(256) void wtrans_all(const float* __restrict__ wq,
                                                  const float* __restrict__ wkv,
                                                  const float* __restrict__ wout,
                                                  u16* __restrict__ wqT,
                                                  u16* __restrict__ wkvT,
                                                  u16* __restrict__ woutT) {
    __shared__ float T[64][65];
    int bid = blockIdx.x;
    const float* in; u16* out; int C;
    if (bid < 256)      { in = wq;   out = wqT;   C = 1024; }
    else if (bid < 768) { in = wkv;  out = wkvT;  C = 2048; bid -= 256; }
    else                { in = wout; out = woutT; C = 1024; bid -= 768; }
    const int R  = 1024;
    const int nc = C >> 6;
    const int c0 = (bid % nc) * 64;
    const int r0 = (bid / nc) * 64;
    const int t  = threadIdx.x;
    const int tx = t & 15, ty = t >> 4;
#pragma unroll
    for (int p = 0; p < 4; ++p) {
        const int r = ty + p * 16;
        float4 v = *reinterpret_cast<const float4*>(in + (size_t)(r0 + r) * C + c0 + tx * 4);
        T[r][tx * 4 + 0] = v.x; T[r][tx * 4 + 1] = v.y;
        T[r][tx * 4 + 2] = v.z; T[r][tx * 4 + 3] = v.w;
    }
    __syncthreads();
#pragma unroll
    for (int p = 0; p < 4; ++p) {
        const int c = ty + p * 16;
        ushort4 o;
        o.x = f2bf(T[tx * 4 + 0][c]); o.y = f2bf(T[tx * 4 + 1][c]);
        o.z = f2bf(T[tx * 4 + 2][c]); o.w = f2bf(T[tx * 4 + 3][c]);
        *reinterpret_cast<ushort4*>(out + (size_t)(c0 + c) * R + r0 + tx * 4) = o;
    }
}

// ---------------------------------------------------------------------------
// Q projection GEMM: Qb = QSCALE * (query_f32 @ wqT^T).  BMT=64.
// A is fp32, cast during staging (fused cast kernel).
// ---------------------------------------------------------------------------
__global__ __launch_bounds__(256) void qgemm(const float* __restrict__ A32,
                                             const u16* __restrict__ Bt,
                                             u16* __restrict__ C) {
    __shared__ u16 As[64 * 64];
    __shared__ u16 Bs[128 * 64];
    const int nwg = gridDim.x * gridDim.y;
    const int id  = blockIdx.y * gridDim.x + blockIdx.x;
    const int sw  = (id & 7) * (nwg >> 3) + (id >> 3);   // chunked per-XCD
    const int bx  = sw % gridDim.x, by = sw / gridDim.x;
    const int tid = threadIdx.x, lane = tid & 63, w = tid >> 6;
    const int wr = w >> 1, wc = w & 1;
    const int row0 = by * 64, col0 = bx * 128;
    const int MROW = wr * 32;

    f32x4 acc[2][4];
#pragma unroll
    for (int m = 0; m < 2; ++m)
#pragma unroll
        for (int n = 0; n < 4; ++n) acc[m][n] = (f32x4){0.f, 0.f, 0.f, 0.f};

    const int lrow = lane >> 3, lcol = (lane & 7) * 8;
    const int arow = tid >> 3, acol = (tid & 7) * 8;

    for (int k0 = 0; k0 < 1024; k0 += 64) {
        __syncthreads();
#pragma unroll
        for (int p = 0; p < 2; ++p) {
            const int r = p * 32 + arow;
            const float* src = A32 + (size_t)(row0 + r) * 1024 + k0 + acol;
            float4 f0 = *reinterpret_cast<const float4*>(src);
            float4 f1 = *reinterpret_cast<const float4*>(src + 4);
            *reinterpret_cast<uint4*>(&As[r * 64 + acol]) = pack8(f0, f1);
        }
#pragma unroll
        for (int p = 0; p < 4; ++p) {
            const int base = w * 512 + p * 2048;
            const int row  = (base >> 6) + lrow;
            gload16(Bt + (size_t)(col0 + row) * 1024 + k0 + lcol, &Bs[base]);
        }
        __syncthreads();
#pragma unroll
        for (int kk = 0; kk < 2; ++kk) {
            bf16x8 af[2], bfr[4];
            const int koff = kk * 32 + (lane >> 4) * 8;
#pragma unroll
            for (int m = 0; m < 2; ++m)
                af[m] = *reinterpret_cast<const bf16x8*>(
                    &As[(MROW + m * 16 + (lane & 15)) * 64 + koff]);
#pragma unroll
            for (int n = 0; n < 4; ++n)
                bfr[n] = *reinterpret_cast<const bf16x8*>(
                    &Bs[(wc * 64 + n * 16 + (lane & 15)) * 64 + koff]);
#pragma unroll
            for (int m = 0; m < 2; ++m)
#pragma unroll
                for (int n = 0; n < 4; ++n)
                    acc[m][n] = __builtin_amdgcn_mfma_f32_16x16x32_bf16(
                        af[m], bfr[n], acc[m][n], 0, 0, 0);
        }
    }
#pragma unroll
    for (int m = 0; m < 2; ++m)
#pragma unroll
        for (int n = 0; n < 4; ++n) {
            const int gc = col0 + wc * 64 + n * 16 + (lane & 15);
#pragma unroll
            for (int r = 0; r < 4; ++r) {
                const int gr = row0 + MROW + m * 16 + (lane >> 4) * 4 + r;
                C[(size_t)gr * 1024 + gc] = f2bf(acc[m][n][r] * QSCALE);
            }
        }
}

// ---------------------------------------------------------------------------
// KV projection GEMM: [8192][2048] = kv_f32 @ wkvT^T.  BMT=128.
// A fp32 cast-in-staging.  Epilogue writes DIRECTLY into the pre-swizzled
// per-tile K/V blobs (kills ktrans/vtrans kernels):
//   K blob slot og=(k,pg): holds K[k][d-granule pg^(k&7)]
//   V blob slot og=(d,pg): holds V^T[d][key-granule pg^(d&7)]
// ---------------------------------------------------------------------------
__global__ __launch_bounds__(256) void kvgemm(const float* __restrict__ A32,
                                              const u16* __restrict__ Bt,
                                              u16* __restrict__ KT,
                                              u16* __restrict__ VT) {
    __shared__ u16 As[128 * 64];
    __shared__ u16 Bs[128 * 64];
    const int nwg = gridDim.x * gridDim.y;
    const int id  = blockIdx.y * gridDim.x + blockIdx.x;
    const int sw  = (id & 7) * (nwg >> 3) + (id >> 3);
    const int bx  = sw % gridDim.x, by = sw / gridDim.x;
    const int tid = threadIdx.x, lane = tid & 63, w = tid >> 6;
    const int wr = w >> 1, wc = w & 1;
    const int row0 = by * 128, col0 = bx * 128;
    const int MROW = wr * 64;

    f32x4 acc[4][4];
#pragma unroll
    for (int m = 0; m < 4; ++m)
#pragma unroll
        for (int n = 0; n < 4; ++n) acc[m][n] = (f32x4){0.f, 0.f, 0.f, 0.f};

    const int lrow = lane >> 3, lcol = (lane & 7) * 8;
    const int arow = tid >> 3, acol = (tid & 7) * 8;

    for (int k0 = 0; k0 < 1024; k0 += 64) {
        __syncthreads();
#pragma unroll
        for (int p = 0; p < 4; ++p) {
            const int r = p * 32 + arow;
            const float* src = A32 + (size_t)(row0 + r) * 1024 + k0 + acol;
            float4 f0 = *reinterpret_cast<const float4*>(src);
            float4 f1 = *reinterpret_cast<const float4*>(src + 4);
            *reinterpret_cast<uint4*>(&As[r * 64 + acol]) = pack8(f0, f1);
        }
#pragma unroll
        for (int p = 0; p < 4; ++p) {
            const int base = w * 512 + p * 2048;
            const int row  = (base >> 6) + lrow;
            gload16(Bt + (size_t)(col0 + row) * 1024 + k0 + lcol, &Bs[base]);
        }
        __syncthreads();
#pragma unroll
        for (int kk = 0; kk < 2; ++kk) {
            bf16x8 af[4], bfr[4];
            const int koff = kk * 32 + (lane >> 4) * 8;
#pragma unroll
            for (int m = 0; m < 4; ++m)
                af[m] = *reinterpret_cast<const bf16x8*>(
                    &As[(MROW + m * 16 + (lane & 15)) * 64 + koff]);
#pragma unroll
            for (int n = 0; n < 4; ++n)
                bfr[n] = *reinterpret_cast<const bf16x8*>(
                    &Bs[(wc * 64 + n * 16 + (lane & 15)) * 64 + koff]);
#pragma unroll
            for (int m = 0; m < 4; ++m)
#pragma unroll
                for (int n = 0; n < 4; ++n)
                    acc[m][n] = __builtin_amdgcn_mfma_f32_16x16x32_bf16(
                        af[m], bfr[n], acc[m][n], 0, 0, 0);
        }
    }

    // epilogue -> blobs
#pragma unroll
    for (int m = 0; m < 4; ++m) {
#pragma unroll
        for (int n = 0; n < 4; ++n) {
            const int gc  = col0 + wc * 64 + n * 16 + (lane & 15);
            const int gr0 = row0 + MROW + m * 16 + (lane >> 4) * 4;
            const int b    = gr0 >> 12;
            const int k    = gr0 & 4095;
            const int kt_i = k >> 6;
            const int k_in = k & 63;
            const int h    = (gc & 1023) >> 6;
            const int d    = gc & 63;
            const size_t blob_off = (((size_t)((b << 4) + h) * 64 + kt_i) << 9) * 8;
            if (gc < 1024) {
                u16* blob = KT + blob_off;
#pragma unroll
                for (int r = 0; r < 4; ++r) {
                    const int kr = k_in + r;
                    const int og = kr * 8 + ((d >> 3) ^ (kr & 7));
                    blob[og * 8 + (d & 7)] = f2bf(acc[m][n][r]);
                }
            } else {
                u16* blob = VT + blob_off;
                const int og = d * 8 + ((k_in >> 3) ^ (d & 7));
                ushort4 pk;
                pk.x = f2bf(acc[m][n][0]); pk.y = f2bf(acc[m][n][1]);
                pk.z = f2bf(acc[m][n][2]); pk.w = f2bf(acc[m][n][3]);
                *reinterpret_cast<ushort4*>(&blob[og * 8 + (k_in & 7)]) = pk;
            }
        }
    }
}

// ---------------------------------------------------------------------------
// Split-K bf16 MFMA flash attention (round-5 structure + VALU diet):
// l-sum via ones-MFMA, v_max3 tree, pointer-incremented blob addressing.
// ---------------------------------------------------------------------------
__global__ __launch_bounds__(256, 4) void attn_mfma(const u16* __restrict__ Qb,
                                                    const u16* __restrict__ KT,
                                                    const u16* __restrict__ VT2,
                                                    float* __restrict__ Op,
                                                    float* __restrict__ m_ws,
                                                    float* __restrict__ l_ws) {
    __shared__ u16 Ks[2][64 * 64];
    __shared__ u16 Vs[2][64 * 64];
    __shared__ u16 Ps[4][16][64];

    const int bid0 = blockIdx.x;
    const int bid  = (bid0 & 7) * 128 + (bid0 >> 3);   // XCD swizzle
    const int qb   = bid & 15;
    const int h    = (bid >> 4) & 15;
    const int b    = (bid >> 8) & 1;
    const int c    = bid >> 9;
    const int tid  = threadIdx.x;
    const int lane = tid & 63;
    const int w    = tid >> 6;
    const int q_l  = lane & 15;
    const int g    = lane >> 4;
    const int qs7  = q_l & 7;
    const int q0   = qb * 64;
    const int bh   = b * NH + h;

    bf16x8 qa0, qa1;
    {
        const u16* qsrc = Qb + (size_t)(b * QL + q0 + w * 16 + q_l) * Hh
                          + h * HD + g * 8;
        qa0 = *reinterpret_cast<const bf16x8*>(qsrc);
        qa1 = *reinterpret_cast<const bf16x8*>(qsrc + 32);
    }
    asm volatile("s_waitcnt vmcnt(0)" ::: "memory");

    bf16x8 ones;
#pragma unroll
    for (int e = 0; e < 8; ++e) ones[e] = (short)0x3F80;   // bf16 1.0

    float m_i = -1e30f;
    f32x4 acc_l = (f32x4){0.f, 0.f, 0.f, 0.f};
    f32x4 acc_o[4];
#pragma unroll
    for (int n = 0; n < 4; ++n) acc_o[n] = (f32x4){0.f, 0.f, 0.f, 0.f};

    // blob pointers, advanced by 4096 u16 per tile
    const size_t tb0 = ((size_t)bh * 64 + c * NTT) * 512 * 8;
    const u16* kq = KT  + tb0;
    const u16* vq = VT2 + tb0;

    auto issue = [&](const u16* kptr, const u16* vptr, int bufi) {
#pragma unroll
        for (int p = 0; p < 2; ++p)
            gload16(kptr + (size_t)(p * 256 + w * 64 + lane) * 8,
                    &Ks[bufi][(p * 256 + w * 64) * 8]);
#pragma unroll
        for (int p = 0; p < 2; ++p)
            gload16(vptr + (size_t)(p * 256 + w * 64 + lane) * 8,
                    &Vs[bufi][(p * 256 + w * 64) * 8]);
    };

    issue(kq, vq, 0);

    for (int t = 0; t < NTT; ++t) {
        const int cur = t & 1;
        __builtin_amdgcn_s_barrier();
        if (t + 1 < NTT) {
            kq += 4096; vq += 4096;
            issue(kq, vq, cur ^ 1);
            asm volatile("s_waitcnt vmcnt(4)" ::: "memory");
        } else {
            asm volatile("s_waitcnt vmcnt(0)" ::: "memory");
        }
        __builtin_amdgcn_sched_barrier(0);
        __builtin_amdgcn_s_barrier();

        // QK^T swapped: s[n][r] = S[key = n*16 + g*4 + r][q_l]
        f32x4 s[4];
        __builtin_amdgcn_s_setprio(1);
#pragma unroll
        for (int n = 0; n < 4; ++n) {
            const int r_ = n * 16 + q_l;
            bf16x8 a0 = *reinterpret_cast<const bf16x8*>(
                &Ks[cur][r_ * 64 + (g ^ qs7) * 8]);
            bf16x8 a1 = *reinterpret_cast<const bf16x8*>(
                &Ks[cur][r_ * 64 + ((g + 4) ^ qs7) * 8]);
            f32x4 z = (f32x4){0.f, 0.f, 0.f, 0.f};
            z = __builtin_amdgcn_mfma_f32_16x16x32_bf16(a0, qa0, z, 0, 0, 0);
            z = __builtin_amdgcn_mfma_f32_16x16x32_bf16(a1, qa1, z, 0, 0, 0);
            s[n] = z;
        }
        __builtin_amdgcn_s_setprio(0);

        // max via v_max3 (9 ops), then 2 shfl
        float c1 = max3f(s[0][0], s[0][1], s[0][2]);
        c1 = max3f(c1, s[0][3], s[1][0]);
        c1 = max3f(c1, s[1][1], s[1][2]);
        c1 = fmaxf(c1, s[1][3]);
        float c2 = max3f(s[2][0], s[2][1], s[2][2]);
        c2 = max3f(c2, s[2][3], s[3][0]);
        c2 = max3f(c2, s[3][1], s[3][2]);
        c2 = fmaxf(c2, s[3][3]);
        float mloc = fmaxf(c1, c2);
        mloc = fmaxf(mloc, __shfl_xor(mloc, 16));
        mloc = fmaxf(mloc, __shfl_xor(mloc, 32));

        if (__any(mloc > m_i + RTHR)) {           // defer-max
            const float mnew = fmaxf(m_i, mloc);
            const float al   = exp2f(m_i - mnew);
            m_i = mnew;
            acc_l[0] *= al; acc_l[1] *= al; acc_l[2] *= al; acc_l[3] *= al;
#pragma unroll
            for (int n = 0; n < 4; ++n) {
                f32x4 tt = acc_o[n];
                tt[0] *= al; tt[1] *= al; tt[2] *= al; tt[3] *= al;
                acc_o[n] = tt;
            }
        }
#pragma unroll
        for (int n = 0; n < 4; ++n)
#pragma unroll
            for (int r = 0; r < 4; ++r) s[n][r] = exp2f(s[n][r] - m_i);

        // pack P -> bf16, swizzled b64 writes (l-sum now via MFMA below)
#pragma unroll
        for (int n = 0; n < 4; ++n) {
            uint2 pk2;
            pk2.x = cvt_pk_bf16(s[n][0], s[n][1]);
            pk2.y = cvt_pk_bf16(s[n][2], s[n][3]);
            const int phys = (2 * n + (g >> 1)) ^ qs7;
            *reinterpret_cast<uint2*>(&Ps[w][q_l][phys * 8 + (g & 1) * 4]) = pk2;
        }
        asm volatile("s_waitcnt lgkmcnt(0)" ::: "memory");
        __builtin_amdgcn_sched_barrier(0);

        // PV swapped + l via ones-MFMA
        __builtin_amdgcn_s_setprio(1);
#pragma unroll
        for (int kf = 0; kf < 2; ++kf) {
            const int phk = ((kf * 4 + g) ^ qs7) * 8;
            bf16x8 pfr = *reinterpret_cast<const bf16x8*>(&Ps[w][q_l][phk]);
            acc_l = __builtin_amdgcn_mfma_f32_16x16x32_bf16(ones, pfr, acc_l, 0, 0, 0);
#pragma unroll
            for (int n = 0; n < 4; ++n) {
                const int d_ = n * 16 + q_l;
                bf16x8 vf = *reinterpret_cast<const bf16x8*>(
                    &Vs[cur][d_ * 64 + phk]);
                acc_o[n] = __builtin_amdgcn_mfma_f32_16x16x32_bf16(
                    vf, pfr, acc_o[n], 0, 0, 0);
            }
        }
        __builtin_amdgcn_s_setprio(0);
    }

    float* opc = Op + (size_t)c * ((size_t)Bb * QL * Hh)
                 + (size_t)(b * QL + q0 + w * 16 + q_l) * Hh + h * HD;
#pragma unroll
    for (int n = 0; n < 4; ++n) {
        float4 v = make_float4(acc_o[n][0], acc_o[n][1], acc_o[n][2], acc_o[n][3]);
        *reinterpret_cast<float4*>(opc + n * 16 + g * 4) = v;
    }
    if (g == 0) {
        const int idx = ((c * Bb + b) * NH + h) * QL + q0 + w * 16 + q_l;
        m_ws[idx] = m_i;
        l_ws[idx] = acc_l[0];
    }
}

// ---------------------------------------------------------------------------
// Output GEMM with FUSED split-K combine in the A-staging:
// A[row][k] = (Op0*w0 + Op1*w1) * inv  (cast to bf16 into LDS).  BMT=64.
// ---------------------------------------------------------------------------
__global__ __launch_bounds__(256) void ogemm(const float* __restrict__ Op,
                                             const float* __restrict__ m_ws,
                                             const float* __restrict__ l_ws,
                                             const u16* __restrict__ Bt,
                                             float* __restrict__ C) {
    __shared__ u16 As[64 * 64];
    __shared__ u16 Bs[128 * 64];
    const int nwg = gridDim.x * gridDim.y;
    const int id  = blockIdx.y * gridDim.x + blockIdx.x;
    const int sw  = (id & 7) * (nwg >> 3) + (id >> 3);
    const int bx  = sw % gridDim.x, by = sw / gridDim.x;
    const int tid = threadIdx.x, lane = tid & 63, w = tid >> 6;
    const int wr = w >> 1, wc = w & 1;
    const int row0 = by * 64, col0 = bx * 128;
    const int MROW = wr * 32;

    f32x4 acc[2][4];
#pragma unroll
    for (int m = 0; m < 2; ++m)
#pragma unroll
        for (int n = 0; n < 4; ++n) acc[m][n] = (f32x4){0.f, 0.f, 0.f, 0.f};

    const int lrow = lane >> 3, lcol = (lane & 7) * 8;
    const int arow = tid >> 3, acol8 = (tid & 7) * 8;

    for (int k0 = 0; k0 < 1024; k0 += 64) {
        __syncthreads();
        const int h_ = k0 >> 6;   // uniform per step
#pragma unroll
        for (int p = 0; p < 2; ++p) {
            const int r    = p * 32 + arow;
            const int grow = row0 + r;
            const int b_   = grow >> 10, q_ = grow & 1023;
            const int idx  = (((b_ << 4) + h_) << 10) + q_;
            const float m0 = m_ws[idx], m1 = m_ws[idx + 32768];
            const float l0 = l_ws[idx], l1 = l_ws[idx + 32768];
            const float ms = fmaxf(m0, m1);
            float a0 = exp2f(m0 - ms), a1 = exp2f(m1 - ms);
            const float inv = 1.f / (l0 * a0 + l1 * a1);
            a0 *= inv; a1 *= inv;
            const float* o0 = Op + (size_t)grow * 1024 + k0 + acol8;
            const float* o1 = o0 + (size_t)Bb * QL * Hh;
            float4 x0 = *reinterpret_cast<const float4*>(o0);
            float4 x1 = *reinterpret_cast<const float4*>(o0 + 4);
            float4 y0 = *reinterpret_cast<const float4*>(o1);
            float4 y1 = *reinterpret_cast<const float4*>(o1 + 4);
            float4 f0 = make_float4(x0.x * a0 + y0.x * a1, x0.y * a0 + y0.y * a1,
                                    x0.z * a0 + y0.z * a1, x0.w * a0 + y0.w * a1);
            float4 f1 = make_float4(x1.x * a0 + y1.x * a1, x1.y * a0 + y1.y * a1,
                                    x1.z * a0 + y1.z * a1, x1.w * a0 + y1.w * a1);
            *reinterpret_cast<uint4*>(&As[r * 64 + acol8]) = pack8(f0, f1);
        }
#pragma unroll
        for (int p = 0; p < 4; ++p) {
            const int base = w * 512 + p * 2048;
            const int row  = (base >> 6) + lrow;
            gload16(Bt + (size_t)(col0 + row) * 1024 + k0 + lcol, &Bs[base]);
        }
        __syncthreads();
#pragma unroll
        for (int kk = 0; kk < 2; ++kk) {
            bf16x8 af[2], bfr[4];
            const int koff = kk * 32 + (lane >> 4) * 8;
#pragma unroll
            for (int m = 0; m < 2; ++m)
                af[m] = *reinterpret_cast<const bf16x8*>(
                    &As[(MROW + m * 16 + (lane & 15)) * 64 + koff]);
#pragma unroll
            for (int n = 0; n < 4; ++n)
                bfr[n] = *reinterpret_cast<const bf16x8*>(
                    &Bs[(wc * 64 + n * 16 + (lane & 15)) * 64 + koff]);
#pragma unroll
            for (int m = 0; m < 2; ++m)
#pragma unroll
                for (int n = 0; n < 4; ++n)
                    acc[m][n] = __builtin_amdgcn_mfma_f32_16x16x32_bf16(
                        af[m], bfr[n], acc[m][n], 0, 0, 0);
        }
    }
#pragma unroll
    for (int m = 0; m < 2; ++m)
#pragma unroll
        for (int n = 0; n < 4; ++n) {
            const int gc = col0 + wc * 64 + n * 16 + (lane & 15);
#pragma unroll
            for (int r = 0; r < 4; ++r) {
                const int gr = row0 + MROW + m * 16 + (lane >> 4) * 4 + r;
                C[(size_t)gr * 1024 + gc] = acc[m][n][r];
            }
        }
}

// ---------------------------------------------------------------------------
// Launch.  Workspace (≤64 MB, NO overlays needed):
//   0-16 KT | 16-32 VT | 32-48 Opart | 48-52 Qb | 52-56 wkvT
//  56-58 wqT | 58-60 woutT | 60-60.25 m_ws | 60.25-60.5 l_ws
// ---------------------------------------------------------------------------
extern "C" void kernel_launch(void* const* d_in, const int* in_sizes, int n_in,
                              void* d_out, int out_size, void* d_ws, size_t ws_size,
                              hipStream_t stream) {
    const float* query     = (const float*)d_in[0];
    const float* key_value = (const float*)d_in[1];
    const float* w_q       = (const float*)d_in[2];
    const float* w_kv      = (const float*)d_in[3];
    const float* w_out     = (const float*)d_in[4];
    float* out = (float*)d_out;

    char* ws = (char*)d_ws;
    const size_t MB = 1024 * 1024;
    u16*   KT    = (u16*)(ws);
    u16*   VT    = (u16*)(ws + 16 * MB);
    float* Opart = (float*)(ws + 32 * MB);
    u16*   Qb    = (u16*)(ws + 48 * MB);
    u16*   wkvT  = (u16*)(ws + 52 * MB);
    u16*   wqT   = (u16*)(ws + 56 * MB);
    u16*   woutT = (u16*)(ws + 58 * MB);
    float* m_wsp = (float*)(ws + 60 * MB);
    float* l_wsp = (float*)(ws + 60 * MB + 256 * 1024);

    dim3 blk(256);

    // 1) all weight transposes in one launch
    wtrans_all<<<1024, blk, 0, stream>>>(w_q, w_kv, w_out, wqT, wkvT, woutT);

    // 2) Q projection (fused fp32 cast, scores pre-scaled into log2 domain)
    qgemm<<<dim3(8, 32), blk, 0, stream>>>(query, wqT, Qb);

    // 3) KV projection (fused cast + fused blob transposes)
    kvgemm<<<dim3(16, 64), blk, 0, stream>>>(key_value, wkvT, KT, VT);

    // 4) split-K flash attention
    attn_mfma<<<dim3(KSPLIT * 512), blk, 0, stream>>>(
        Qb, KT, VT, Opart, m_wsp, l_wsp);

    // 5) output GEMM (fused split-K combine in A-staging)
    ogemm<<<dim3(8, 32), blk, 0, stream>>>(Opart, m_wsp, l_wsp, woutT, out);
}

// Round 7
// 183.683 us; speedup vs baseline: 7.1828x; 1.1038x over previous
//
#include <hip/hip_runtime.h>

// Problem constants (CompactCrossAttention)
#define Bb   2
#define QL   1024
#define KL   4096
#define Hh   1024
#define NH   16
#define HD   64

#define KSPLIT 2
#define CHUNK  (KL / KSPLIT)   // 2048 keys per block
#define NTT    (CHUNK / 64)    // 32 tiles of 64 keys

typedef unsigned short u16;
typedef __attribute__((ext_vector_type(8))) short bf16x8;   // MFMA A/B frag
typedef __attribute__((ext_vector_type(8))) unsigned short usv8;
typedef __attribute__((ext_vector_type(4))) float f32x4;    // MFMA C/D frag

#define QSCALE 0.1803368801111204f   // 0.125 * log2(e): scores in log2 domain
#define RTHR   11.0f                 // defer-max threshold (log2 units)

__device__ __forceinline__ u16 f2bf(float f) {
    union { float f; unsigned int u; } v; v.f = f;
    unsigned int r = (v.u + 0x7FFFu + ((v.u >> 16) & 1u)) >> 16;
    return (u16)r;
}

__device__ __forceinline__ unsigned int cvt_pk_bf16(float lo, float hi) {
    unsigned int r;
    asm("v_cvt_pk_bf16_f32 %0, %1, %2" : "=v"(r) : "v"(lo), "v"(hi));
    return r;
}

__device__ __forceinline__ float max3f(float a, float b, float c) {
    float r;
    asm("v_max3_f32 %0, %1, %2, %3" : "=v"(r) : "v"(a), "v"(b), "v"(c));
    return r;
}

__device__ __forceinline__ void gload16(const void* g, void* l) {
    __builtin_amdgcn_global_load_lds(
        (const __attribute__((address_space(1))) void*)g,
        (__attribute__((address_space(3))) void*)l, 16, 0, 0);
}

// pack 8 fp32 -> 8 bf16 (uint4)
__device__ __forceinline__ uint4 pack8(const float4& f0, const float4& f1) {
    uint4 o;
    o.x = cvt_pk_bf16(f0.x, f0.y);
    o.y = cvt_pk_bf16(f0.z, f0.w);
    o.z = cvt_pk_bf16(f1.x, f1.y);
    o.w = cvt_pk_bf16(f1.z, f1.w);
    return o;
}

// ---------------------------------------------------------------------------
// All three weight transposes (fp32 [R][C] -> bf16 [C][R]) in ONE launch.
// Output rows are GRANULE-SWIZZLED: within each 64-k panel of weight-row n,
// logical k-granule gl (8 elems) sits at physical slot gl ^ (n&7).  This is
// the inverse-permuted global source that makes gload16-staged LDS tiles
// bank-conflict-free under the G ^ (lane&7) fragment reads (rule 21).
// grid 1024: [0,256) w_q, [256,768) w_kv, [768,1024) w_out.
// ---------------------------------------------------------------------------
__global__ __launch_bounds__(256) void wtrans_all(const float* __restrict__ wq,
                                                  const float* __restrict__ wkv,
                                                  const float* __restrict__ wout,
                                                  u16* __restrict__ wqT,
                                                  u16* __restrict__ wkvT,
                                                  u16* __restrict__ woutT) {
    __shared__ float T[64][65];
    int bid = blockIdx.x;
    const float* in; u16* out; int C;
    if (bid < 256)      { in = wq;   out = wqT;   C = 1024; }
    else if (bid < 768) { in = wkv;  out = wkvT;  C = 2048; bid -= 256; }
    else                { in = wout; out = woutT; C = 1024; bid -= 768; }
    const int nc = C >> 6;
    const int c0 = (bid % nc) * 64;
    const int r0 = (bid / nc) * 64;
    const int t  = threadIdx.x;
    const int tx = t & 15, ty = t >> 4;
#pragma unroll
    for (int p = 0; p < 4; ++p) {
        const int r = ty + p * 16;
        float4 v = *reinterpret_cast<const float4*>(in + (size_t)(r0 + r) * C + c0 + tx * 4);
        T[r][tx * 4 + 0] = v.x; T[r][tx * 4 + 1] = v.y;
        T[r][tx * 4 + 2] = v.z; T[r][tx * 4 + 3] = v.w;
    }
    __syncthreads();
#pragma unroll
    for (int p = 0; p < 4; ++p) {
        const int c = ty + p * 16;
        const int n = c0 + c;
        ushort4 o;
        o.x = f2bf(T[tx * 4 + 0][c]); o.y = f2bf(T[tx * 4 + 1][c]);
        o.z = f2bf(T[tx * 4 + 2][c]); o.w = f2bf(T[tx * 4 + 3][c]);
        const int kb   = r0 + tx * 4;
        const int kout = (kb & ~63) | ((((kb >> 3) & 7) ^ (n & 7)) << 3) | (kb & 7);
        *reinterpret_cast<ushort4*>(out + (size_t)n * 1024 + kout) = o;
    }
}

// ---------------------------------------------------------------------------
// Q projection GEMM: Qb = QSCALE * (query_f32 @ wqT^T).  BMT=64.
// A fp32 cast-in-staging with XOR-swizzled LDS writes; swizzled frag reads.
// ---------------------------------------------------------------------------
__global__ __launch_bounds__(256) void qgemm(const float* __restrict__ A32,
                                             const u16* __restrict__ Bt,
                                             u16* __restrict__ C) {
    __shared__ u16 As[64 * 64];
    __shared__ u16 Bs[128 * 64];
    const int nwg = gridDim.x * gridDim.y;
    const int id  = blockIdx.y * gridDim.x + blockIdx.x;
    const int sw  = (id & 7) * (nwg >> 3) + (id >> 3);   // chunked per-XCD
    const int bx  = sw % gridDim.x, by = sw / gridDim.x;
    const int tid = threadIdx.x, lane = tid & 63, w = tid >> 6;
    const int wr = w >> 1, wc = w & 1;
    const int row0 = by * 64, col0 = bx * 128;
    const int MROW = wr * 32;
    const int x7   = lane & 7;

    f32x4 acc[2][4];
#pragma unroll
    for (int m = 0; m < 2; ++m)
#pragma unroll
        for (int n = 0; n < 4; ++n) acc[m][n] = (f32x4){0.f, 0.f, 0.f, 0.f};

    const int lrow = lane >> 3, lcol = (lane & 7) * 8;
    const int arow = tid >> 3, acol8 = (tid & 7) * 8;
    const int aphys = acol8 ^ ((arow & 7) << 3);

    for (int k0 = 0; k0 < 1024; k0 += 64) {
        __syncthreads();
#pragma unroll
        for (int p = 0; p < 2; ++p) {
            const int r = p * 32 + arow;
            const float* src = A32 + (size_t)(row0 + r) * 1024 + k0 + acol8;
            float4 f0 = *reinterpret_cast<const float4*>(src);
            float4 f1 = *reinterpret_cast<const float4*>(src + 4);
            *reinterpret_cast<uint4*>(&As[r * 64 + aphys]) = pack8(f0, f1);
        }
#pragma unroll
        for (int p = 0; p < 4; ++p) {
            const int base = w * 512 + p * 2048;
            const int row  = (base >> 6) + lrow;
            gload16(Bt + (size_t)(col0 + row) * 1024 + k0 + lcol, &Bs[base]);
        }
        __syncthreads();
#pragma unroll
        for (int kk = 0; kk < 2; ++kk) {
            bf16x8 af[2], bfr[4];
            const int G = ((kk * 4 + (lane >> 4)) ^ x7) * 8;
#pragma unroll
            for (int m = 0; m < 2; ++m)
                af[m] = *reinterpret_cast<const bf16x8*>(
                    &As[(MROW + m * 16 + (lane & 15)) * 64 + G]);
#pragma unroll
            for (int n = 0; n < 4; ++n)
                bfr[n] = *reinterpret_cast<const bf16x8*>(
                    &Bs[(wc * 64 + n * 16 + (lane & 15)) * 64 + G]);
#pragma unroll
            for (int m = 0; m < 2; ++m)
#pragma unroll
                for (int n = 0; n < 4; ++n)
                    acc[m][n] = __builtin_amdgcn_mfma_f32_16x16x32_bf16(
                        af[m], bfr[n], acc[m][n], 0, 0, 0);
        }
    }
#pragma unroll
    for (int m = 0; m < 2; ++m)
#pragma unroll
        for (int n = 0; n < 4; ++n) {
            const int gc = col0 + wc * 64 + n * 16 + (lane & 15);
#pragma unroll
            for (int r = 0; r < 4; ++r) {
                const int gr = row0 + MROW + m * 16 + (lane >> 4) * 4 + r;
                C[(size_t)gr * 1024 + gc] = f2bf(acc[m][n][r] * QSCALE);
            }
        }
}

// ---------------------------------------------------------------------------
// KV projection GEMM: [8192][2048] = kv_f32 @ wkvT^T.  BMT=128.
// Col tiles 0-7 are pure-K blocks, 8-15 pure-V.  K blocks compute with
// SWAPPED operands (D rows = d-dim) so each thread owns 4 consecutive d
// -> vectorized ushort4 blob stores for BOTH K and V.
//   K blob slot og=(k,pg): holds K[k][d-granule pg^(k&7)]
//   V blob slot og=(d,pg): holds V^T[d][key-granule pg^(d&7)]
// ---------------------------------------------------------------------------
__global__ __launch_bounds__(256) void kvgemm(const float* __restrict__ A32,
                                              const u16* __restrict__ Bt,
                                              u16* __restrict__ KT,
                                              u16* __restrict__ VT) {
    __shared__ u16 As[128 * 64];
    __shared__ u16 Bs[128 * 64];
    const int nwg = gridDim.x * gridDim.y;
    const int id  = blockIdx.y * gridDim.x + blockIdx.x;
    const int sw  = (id & 7) * (nwg >> 3) + (id >> 3);
    const int bx  = sw % gridDim.x, by = sw / gridDim.x;
    const int tid = threadIdx.x, lane = tid & 63, w = tid >> 6;
    const int wr = w >> 1, wc = w & 1;
    const int row0 = by * 128, col0 = bx * 128;
    const int MROW = wr * 64;
    const int x7   = lane & 7;

    f32x4 acc[4][4];
#pragma unroll
    for (int m = 0; m < 4; ++m)
#pragma unroll
        for (int n = 0; n < 4; ++n) acc[m][n] = (f32x4){0.f, 0.f, 0.f, 0.f};

    const int lrow = lane >> 3, lcol = (lane & 7) * 8;
    const int arow = tid >> 3, acol8 = (tid & 7) * 8;
    const int aphys = acol8 ^ ((arow & 7) << 3);

    auto stage = [&](int k0) {
        __syncthreads();
#pragma unroll
        for (int p = 0; p < 4; ++p) {
            const int r = p * 32 + arow;
            const float* src = A32 + (size_t)(row0 + r) * 1024 + k0 + acol8;
            float4 f0 = *reinterpret_cast<const float4*>(src);
            float4 f1 = *reinterpret_cast<const float4*>(src + 4);
            *reinterpret_cast<uint4*>(&As[r * 64 + aphys]) = pack8(f0, f1);
        }
#pragma unroll
        for (int p = 0; p < 4; ++p) {
            const int base = w * 512 + p * 2048;
            const int row  = (base >> 6) + lrow;
            gload16(Bt + (size_t)(col0 + row) * 1024 + k0 + lcol, &Bs[base]);
        }
        __syncthreads();
    };

    if (col0 < 1024) {
        // ---- K orientation: acc[m][n] = mfma(bfr[n], af[m]) ----
        for (int k0 = 0; k0 < 1024; k0 += 64) {
            stage(k0);
#pragma unroll
            for (int kk = 0; kk < 2; ++kk) {
                bf16x8 af[4], bfr[4];
                const int G = ((kk * 4 + (lane >> 4)) ^ x7) * 8;
#pragma unroll
                for (int m = 0; m < 4; ++m)
                    af[m] = *reinterpret_cast<const bf16x8*>(
                        &As[(MROW + m * 16 + (lane & 15)) * 64 + G]);
#pragma unroll
                for (int n = 0; n < 4; ++n)
                    bfr[n] = *reinterpret_cast<const bf16x8*>(
                        &Bs[(wc * 64 + n * 16 + (lane & 15)) * 64 + G]);
#pragma unroll
                for (int m = 0; m < 4; ++m)
#pragma unroll
                    for (int n = 0; n < 4; ++n)
                        acc[m][n] = __builtin_amdgcn_mfma_f32_16x16x32_bf16(
                            bfr[n], af[m], acc[m][n], 0, 0, 0);
            }
        }
        // epilogue: thread has 4 consecutive d (reg dim), one k (lane&15)
#pragma unroll
        for (int m = 0; m < 4; ++m) {
            const int gr  = row0 + MROW + m * 16 + (lane & 15);
            const int b   = gr >> 12;
            const int k   = gr & 4095;
            const int kt_i = k >> 6, k_in = k & 63;
#pragma unroll
            for (int n = 0; n < 4; ++n) {
                const int gc0 = col0 + wc * 64 + n * 16 + (lane >> 4) * 4;
                const int h   = gc0 >> 6, d0 = gc0 & 63;
                u16* blob = KT + (((size_t)((b << 4) + h) * 64 + kt_i) << 9) * 8;
                const int og = k_in * 8 + ((d0 >> 3) ^ (k_in & 7));
                ushort4 pk;
                pk.x = f2bf(acc[m][n][0]); pk.y = f2bf(acc[m][n][1]);
                pk.z = f2bf(acc[m][n][2]); pk.w = f2bf(acc[m][n][3]);
                *reinterpret_cast<ushort4*>(&blob[og * 8 + (d0 & 7)]) = pk;
            }
        }
    } else {
        // ---- V orientation: normal acc[m][n] = mfma(af[m], bfr[n]) ----
        for (int k0 = 0; k0 < 1024; k0 += 64) {
            stage(k0);
#pragma unroll
            for (int kk = 0; kk < 2; ++kk) {
                bf16x8 af[4], bfr[4];
                const int G = ((kk * 4 + (lane >> 4)) ^ x7) * 8;
#pragma unroll
                for (int m = 0; m < 4; ++m)
                    af[m] = *reinterpret_cast<const bf16x8*>(
                        &As[(MROW + m * 16 + (lane & 15)) * 64 + G]);
#pragma unroll
                for (int n = 0; n < 4; ++n)
                    bfr[n] = *reinterpret_cast<const bf16x8*>(
                        &Bs[(wc * 64 + n * 16 + (lane & 15)) * 64 + G]);
#pragma unroll
                for (int m = 0; m < 4; ++m)
#pragma unroll
                    for (int n = 0; n < 4; ++n)
                        acc[m][n] = __builtin_amdgcn_mfma_f32_16x16x32_bf16(
                            af[m], bfr[n], acc[m][n], 0, 0, 0);
            }
        }
        // epilogue: thread has 4 consecutive k (reg dim), one d (lane&15)
#pragma unroll
        for (int m = 0; m < 4; ++m) {
            const int gr0 = row0 + MROW + m * 16 + (lane >> 4) * 4;
            const int b   = gr0 >> 12;
            const int k   = gr0 & 4095;
            const int kt_i = k >> 6, k_in = k & 63;
#pragma unroll
            for (int n = 0; n < 4; ++n) {
                const int gc = col0 + wc * 64 + n * 16 + (lane & 15);
                const int h  = (gc & 1023) >> 6, d = gc & 63;
                u16* blob = VT + (((size_t)((b << 4) + h) * 64 + kt_i) << 9) * 8;
                const int og = d * 8 + ((k_in >> 3) ^ (d & 7));
                ushort4 pk;
                pk.x = f2bf(acc[m][n][0]); pk.y = f2bf(acc[m][n][1]);
                pk.z = f2bf(acc[m][n][2]); pk.w = f2bf(acc[m][n][3]);
                *reinterpret_cast<ushort4*>(&blob[og * 8 + (k_in & 7)]) = pk;
            }
        }
    }
}

// ---------------------------------------------------------------------------
// Split-K bf16 MFMA flash attention (unchanged from round 6).
// ---------------------------------------------------------------------------
__global__ __launch_bounds__(256, 4) void attn_mfma(const u16* __restrict__ Qb,
                                                    const u16* __restrict__ KT,
                                                    const u16* __restrict__ VT2,
                                                    float* __restrict__ Op,
                                                    float* __restrict__ m_ws,
                                                    float* __restrict__ l_ws) {
    __shared__ u16 Ks[2][64 * 64];
    __shared__ u16 Vs[2][64 * 64];
    __shared__ u16 Ps[4][16][64];

    const int bid0 = blockIdx.x;
    const int bid  = (bid0 & 7) * 128 + (bid0 >> 3);   // XCD swizzle
    const int qb   = bid & 15;
    const int h    = (bid >> 4) & 15;
    const int b    = (bid >> 8) & 1;
    const int c    = bid >> 9;
    const int tid  = threadIdx.x;
    const int lane = tid & 63;
    const int w    = tid >> 6;
    const int q_l  = lane & 15;
    const int g    = lane >> 4;
    const int qs7  = q_l & 7;
    const int q0   = qb * 64;
    const int bh   = b * NH + h;

    bf16x8 qa0, qa1;
    {
        const u16* qsrc = Qb + (size_t)(b * QL + q0 + w * 16 + q_l) * Hh
                          + h * HD + g * 8;
        qa0 = *reinterpret_cast<const bf16x8*>(qsrc);
        qa1 = *reinterpret_cast<const bf16x8*>(qsrc + 32);
    }
    asm volatile("s_waitcnt vmcnt(0)" ::: "memory");

    bf16x8 ones;
#pragma unroll
    for (int e = 0; e < 8; ++e) ones[e] = (short)0x3F80;   // bf16 1.0

    float m_i = -1e30f;
    f32x4 acc_l = (f32x4){0.f, 0.f, 0.f, 0.f};
    f32x4 acc_o[4];
#pragma unroll
    for (int n = 0; n < 4; ++n) acc_o[n] = (f32x4){0.f, 0.f, 0.f, 0.f};

    const size_t tb0 = ((size_t)bh * 64 + c * NTT) * 512 * 8;
    const u16* kq = KT  + tb0;
    const u16* vq = VT2 + tb0;

    auto issue = [&](const u16* kptr, const u16* vptr, int bufi) {
#pragma unroll
        for (int p = 0; p < 2; ++p)
            gload16(kptr + (size_t)(p * 256 + w * 64 + lane) * 8,
                    &Ks[bufi][(p * 256 + w * 64) * 8]);
#pragma unroll
        for (int p = 0; p < 2; ++p)
            gload16(vptr + (size_t)(p * 256 + w * 64 + lane) * 8,
                    &Vs[bufi][(p * 256 + w * 64) * 8]);
    };

    issue(kq, vq, 0);

    for (int t = 0; t < NTT; ++t) {
        const int cur = t & 1;
        __builtin_amdgcn_s_barrier();
        if (t + 1 < NTT) {
            kq += 4096; vq += 4096;
            issue(kq, vq, cur ^ 1);
            asm volatile("s_waitcnt vmcnt(4)" ::: "memory");
        } else {
            asm volatile("s_waitcnt vmcnt(0)" ::: "memory");
        }
        __builtin_amdgcn_sched_barrier(0);
        __builtin_amdgcn_s_barrier();

        // QK^T swapped: s[n][r] = S[key = n*16 + g*4 + r][q_l]
        f32x4 s[4];
        __builtin_amdgcn_s_setprio(1);
#pragma unroll
        for (int n = 0; n < 4; ++n) {
            const int r_ = n * 16 + q_l;
            bf16x8 a0 = *reinterpret_cast<const bf16x8*>(
                &Ks[cur][r_ * 64 + (g ^ qs7) * 8]);
            bf16x8 a1 = *reinterpret_cast<const bf16x8*>(
                &Ks[cur][r_ * 64 + ((g + 4) ^ qs7) * 8]);
            f32x4 z = (f32x4){0.f, 0.f, 0.f, 0.f};
            z = __builtin_amdgcn_mfma_f32_16x16x32_bf16(a0, qa0, z, 0, 0, 0);
            z = __builtin_amdgcn_mfma_f32_16x16x32_bf16(a1, qa1, z, 0, 0, 0);
            s[n] = z;
        }
        __builtin_amdgcn_s_setprio(0);

        // max via v_max3 tree, then 2 shfl
        float c1 = max3f(s[0][0], s[0][1], s[0][2]);
        c1 = max3f(c1, s[0][3], s[1][0]);
        c1 = max3f(c1, s[1][1], s[1][2]);
        c1 = fmaxf(c1, s[1][3]);
        float c2 = max3f(s[2][0], s[2][1], s[2][2]);
        c2 = max3f(c2, s[2][3], s[3][0]);
        c2 = max3f(c2, s[3][1], s[3][2]);
        c2 = fmaxf(c2, s[3][3]);
        float mloc = fmaxf(c1, c2);
        mloc = fmaxf(mloc, __shfl_xor(mloc, 16));
        mloc = fmaxf(mloc, __shfl_xor(mloc, 32));

        if (__any(mloc > m_i + RTHR)) {           // defer-max
            const float mnew = fmaxf(m_i, mloc);
            const float al   = exp2f(m_i - mnew);
            m_i = mnew;
            acc_l[0] *= al; acc_l[1] *= al; acc_l[2] *= al; acc_l[3] *= al;
#pragma unroll
            for (int n = 0; n < 4; ++n) {
                f32x4 tt = acc_o[n];
                tt[0] *= al; tt[1] *= al; tt[2] *= al; tt[3] *= al;
                acc_o[n] = tt;
            }
        }
#pragma unroll
        for (int n = 0; n < 4; ++n)
#pragma unroll
            for (int r = 0; r < 4; ++r) s[n][r] = exp2f(s[n][r] - m_i);

        // pack P -> bf16, swizzled b64 writes
#pragma unroll
        for (int n = 0; n < 4; ++n) {
            uint2 pk2;
            pk2.x = cvt_pk_bf16(s[n][0], s[n][1]);
            pk2.y = cvt_pk_bf16(s[n][2], s[n][3]);
            const int phys = (2 * n + (g >> 1)) ^ qs7;
            *reinterpret_cast<uint2*>(&Ps[w][q_l][phys * 8 + (g & 1) * 4]) = pk2;
        }
        asm volatile("s_waitcnt lgkmcnt(0)" ::: "memory");
        __builtin_amdgcn_sched_barrier(0);

        // PV swapped + l via ones-MFMA
        __builtin_amdgcn_s_setprio(1);
#pragma unroll
        for (int kf = 0; kf < 2; ++kf) {
            const int phk = ((kf * 4 + g) ^ qs7) * 8;
            bf16x8 pfr = *reinterpret_cast<const bf16x8*>(&Ps[w][q_l][phk]);
            acc_l = __builtin_amdgcn_mfma_f32_16x16x32_bf16(ones, pfr, acc_l, 0, 0, 0);
#pragma unroll
            for (int n = 0; n < 4; ++n) {
                const int d_ = n * 16 + q_l;
                bf16x8 vf = *reinterpret_cast<const bf16x8*>(
                    &Vs[cur][d_ * 64 + phk]);
                acc_o[n] = __builtin_amdgcn_mfma_f32_16x16x32_bf16(
                    vf, pfr, acc_o[n], 0, 0, 0);
            }
        }
        __builtin_amdgcn_s_setprio(0);
    }

    float* opc = Op + (size_t)c * ((size_t)Bb * QL * Hh)
                 + (size_t)(b * QL + q0 + w * 16 + q_l) * Hh + h * HD;
#pragma unroll
    for (int n = 0; n < 4; ++n) {
        float4 v = make_float4(acc_o[n][0], acc_o[n][1], acc_o[n][2], acc_o[n][3]);
        *reinterpret_cast<float4*>(opc + n * 16 + g * 4) = v;
    }
    if (g == 0) {
        const int idx = ((c * Bb + b) * NH + h) * QL + q0 + w * 16 + q_l;
        m_ws[idx] = m_i;
        l_ws[idx] = acc_l[0];
    }
}

// ---------------------------------------------------------------------------
// Output GEMM with FUSED split-K combine in A-staging.  BMT=64.
// ---------------------------------------------------------------------------
__global__ __launch_bounds__(256) void ogemm(const float* __restrict__ Op,
                                             const float* __restrict__ m_ws,
                                             const float* __restrict__ l_ws,
                                             const u16* __restrict__ Bt,
                                             float* __restrict__ C) {
    __shared__ u16 As[64 * 64];
    __shared__ u16 Bs[128 * 64];
    const int nwg = gridDim.x * gridDim.y;
    const int id  = blockIdx.y * gridDim.x + blockIdx.x;
    const int sw  = (id & 7) * (nwg >> 3) + (id >> 3);
    const int bx  = sw % gridDim.x, by = sw / gridDim.x;
    const int tid = threadIdx.x, lane = tid & 63, w = tid >> 6;
    const int wr = w >> 1, wc = w & 1;
    const int row0 = by * 64, col0 = bx * 128;
    const int MROW = wr * 32;
    const int x7   = lane & 7;

    f32x4 acc[2][4];
#pragma unroll
    for (int m = 0; m < 2; ++m)
#pragma unroll
        for (int n = 0; n < 4; ++n) acc[m][n] = (f32x4){0.f, 0.f, 0.f, 0.f};

    const int lrow = lane >> 3, lcol = (lane & 7) * 8;
    const int arow = tid >> 3, acol8 = (tid & 7) * 8;
    const int aphys = acol8 ^ ((arow & 7) << 3);

    for (int k0 = 0; k0 < 1024; k0 += 64) {
        __syncthreads();
        const int h_ = k0 >> 6;   // uniform per step
#pragma unroll
        for (int p = 0; p < 2; ++p) {
            const int r    = p * 32 + arow;
            const int grow = row0 + r;
            const int b_   = grow >> 10, q_ = grow & 1023;
            const int idx  = (((b_ << 4) + h_) << 10) + q_;
            const float m0 = m_ws[idx], m1 = m_ws[idx + 32768];
            const float l0 = l_ws[idx], l1 = l_ws[idx + 32768];
            const float ms = fmaxf(m0, m1);
            float a0 = exp2f(m0 - ms), a1 = exp2f(m1 - ms);
            const float inv = 1.f / (l0 * a0 + l1 * a1);
            a0 *= inv; a1 *= inv;
            const float* o0 = Op + (size_t)grow * 1024 + k0 + acol8;
            const float* o1 = o0 + (size_t)Bb * QL * Hh;
            float4 x0 = *reinterpret_cast<const float4*>(o0);
            float4 x1 = *reinterpret_cast<const float4*>(o0 + 4);
            float4 y0 = *reinterpret_cast<const float4*>(o1);
            float4 y1 = *reinterpret_cast<const float4*>(o1 + 4);
            float4 f0 = make_float4(x0.x * a0 + y0.x * a1, x0.y * a0 + y0.y * a1,
                                    x0.z * a0 + y0.z * a1, x0.w * a0 + y0.w * a1);
            float4 f1 = make_float4(x1.x * a0 + y1.x * a1, x1.y * a0 + y1.y * a1,
                                    x1.z * a0 + y1.z * a1, x1.w * a0 + y1.w * a1);
            *reinterpret_cast<uint4*>(&As[r * 64 + aphys]) = pack8(f0, f1);
        }
#pragma unroll
        for (int p = 0; p < 4; ++p) {
            const int base = w * 512 + p * 2048;
            const int row  = (base >> 6) + lrow;
            gload16(Bt + (size_t)(col0 + row) * 1024 + k0 + lcol, &Bs[base]);
        }
        __syncthreads();
#pragma unroll
        for (int kk = 0; kk < 2; ++kk) {
            bf16x8 af[2], bfr[4];
            const int G = ((kk * 4 + (lane >> 4)) ^ x7) * 8;
#pragma unroll
            for (int m = 0; m < 2; ++m)
                af[m] = *reinterpret_cast<const bf16x8*>(
                    &As[(MROW + m * 16 + (lane & 15)) * 64 + G]);
#pragma unroll
            for (int n = 0; n < 4; ++n)
                bfr[n] = *reinterpret_cast<const bf16x8*>(
                    &Bs[(wc * 64 + n * 16 + (lane & 15)) * 64 + G]);
#pragma unroll
            for (int m = 0; m < 2; ++m)
#pragma unroll
                for (int n = 0; n < 4; ++n)
                    acc[m][n] = __builtin_amdgcn_mfma_f32_16x16x32_bf16(
                        af[m], bfr[n], acc[m][n], 0, 0, 0);
        }
    }
#pragma unroll
    for (int m = 0; m < 2; ++m)
#pragma unroll
        for (int n = 0; n < 4; ++n) {
            const int gc = col0 + wc * 64 + n * 16 + (lane & 15);
#pragma unroll
            for (int r = 0; r < 4; ++r) {
                const int gr = row0 + MROW + m * 16 + (lane >> 4) * 4 + r;
                C[(size_t)gr * 1024 + gc] = acc[m][n][r];
            }
        }
}

// ---------------------------------------------------------------------------
// Launch.  Workspace:
//   0-16 KT | 16-32 VT | 32-48 Opart | 48-52 Qb | 52-56 wkvT
//  56-58 wqT | 58-60 woutT | 60-60.25 m_ws | 60.25-60.5 l_ws
// ---------------------------------------------------------------------------
extern "C" void kernel_launch(void* const* d_in, const int* in_sizes, int n_in,
                              void* d_out, int out_size, void* d_ws, size_t ws_size,
                              hipStream_t stream) {
    const float* query     = (const float*)d_in[0];
    const float* key_value = (const float*)d_in[1];
    const float* w_q       = (const float*)d_in[2];
    const float* w_kv      = (const float*)d_in[3];
    const float* w_out     = (const float*)d_in[4];
    float* out = (float*)d_out;

    char* ws = (char*)d_ws;
    const size_t MB = 1024 * 1024;
    u16*   KT    = (u16*)(ws);
    u16*   VT    = (u16*)(ws + 16 * MB);
    float* Opart = (float*)(ws + 32 * MB);
    u16*   Qb    = (u16*)(ws + 48 * MB);
    u16*   wkvT  = (u16*)(ws + 52 * MB);
    u16*   wqT   = (u16*)(ws + 56 * MB);
    u16*   woutT = (u16*)(ws + 58 * MB);
    float* m_wsp = (float*)(ws + 60 * MB);
    float* l_wsp = (float*)(ws + 60 * MB + 256 * 1024);

    dim3 blk(256);

    // 1) all weight transposes (swizzled layout) in one launch
    wtrans_all<<<1024, blk, 0, stream>>>(w_q, w_kv, w_out, wqT, wkvT, woutT);

    // 2) Q projection (fused fp32 cast; log2-domain scale)
    qgemm<<<dim3(8, 32), blk, 0, stream>>>(query, wqT, Qb);

    // 3) KV projection (fused cast + fused swizzled blob epilogues)
    kvgemm<<<dim3(16, 64), blk, 0, stream>>>(key_value, wkvT, KT, VT);

    // 4) split-K flash attention
    attn_mfma<<<dim3(KSPLIT * 512), blk, 0, stream>>>(
        Qb, KT, VT, Opart, m_wsp, l_wsp);

    // 5) output GEMM (fused split-K combine in A-staging)
    ogemm<<<dim3(8, 32), blk, 0, stream>>>(Opart, m_wsp, l_wsp, woutT, out);
}